// Round 7
// baseline (656.607 us; speedup 1.0000x reference)
//
#include <hip/hip_runtime.h>
#include <hip/hip_bf16.h>
#include <hip/hip_fp16.h>

// VSSBlock: B=2 H=64 W=64 C=192 DM=384 N=16 R=12 K=4 L=4096
// R15 (on R14 base, 244.2us): scan0+combine+scan1 fused into ONE kernel via decoupled
//     lookback (rocPRIM-style): local scan (delta/u stashed in packed 16-bit regs, B|C
//     rows in LDS), publish (E,cum) agent-release, lookback with inclusive short-circuit
//     (pow16 composition), replay from h_in, store y. Tile ids via global atomic counter
//     (deadlock-free under partial residency). Saves scan0's full re-read pass, the 50MB
//     Eb round trip, the combine kernel, and one launch.

typedef __attribute__((ext_vector_type(8))) short short8;     // 8 bf16 = 4 VGPRs
typedef __attribute__((ext_vector_type(4))) float floatx4;    // fp32 accum frag

// ---------------- LayerNorm (pre-norm, eps 1e-6), C=192 -> bf16 ----------------
__global__ __launch_bounds__(256) void k_ln(const float* __restrict__ in,
                                            const float* __restrict__ g,
                                            const float* __restrict__ be,
                                            __hip_bfloat16* __restrict__ out) {
  int row = blockIdx.x * 4 + (threadIdx.x >> 6);
  int lane = threadIdx.x & 63;
  const float* x = in + (long)row * 192;
  float v0 = x[lane], v1 = x[lane + 64], v2 = x[lane + 128];
  float s = v0 + v1 + v2;
  float s2 = v0 * v0 + v1 * v1 + v2 * v2;
  #pragma unroll
  for (int o = 32; o > 0; o >>= 1) { s += __shfl_xor(s, o); s2 += __shfl_xor(s2, o); }
  float mu = s * (1.f / 192.f);
  float var = s2 * (1.f / 192.f) - mu * mu;
  float r = rsqrtf(var + 1e-6f);
  __hip_bfloat16* op = out + (long)row * 192;
  op[lane]       = __float2bfloat16((v0 - mu) * r * g[lane]       + be[lane]);
  op[lane + 64]  = __float2bfloat16((v1 - mu) * r * g[lane + 64]  + be[lane + 64]);
  op[lane + 128] = __float2bfloat16((v2 - mu) * r * g[lane + 128] + be[lane + 128]);
}

// ---------------- pack weights -> bf16, transposed to (N x K) ----------------
__global__ __launch_bounds__(256) void k_packw(const float* __restrict__ ipw,
                                               const float* __restrict__ xpw,
                                               const float* __restrict__ opw,
                                               __hip_bfloat16* __restrict__ Wt1,
                                               __hip_bfloat16* __restrict__ Wt2,
                                               __hip_bfloat16* __restrict__ Wt3) {
  int idx = blockIdx.x * 256 + threadIdx.x;
  if (idx < 147456) {                       // Wt1[n][k] = ipw[k][n]
    int n = idx / 192, k = idx - n * 192;
    Wt1[idx] = __float2bfloat16(ipw[(long)k * 768 + n]);
  } else if (idx < 147456 + 73728) {        // Wt2[j][d]
    int t = idx - 147456;
    int j = t / 384;
    float v = (j < 176) ? xpw[t] : 0.f;
    Wt2[t] = __float2bfloat16(v);
  } else if (idx < 147456 + 73728 + 73728) {// Wt3[n][k] = opw[k][n]
    int t = idx - 147456 - 73728;
    int n = t / 384, k = t - n * 384;
    Wt3[t] = __float2bfloat16(opw[(long)k * 192 + n]);
  }
}

// direction map (involutions): pixel p <-> scan position l
__device__ __forceinline__ int inv_dir(int k, int p) {
  int pt = ((p & 63) << 6) | (p >> 6);
  if (k == 0) return p;
  if (k == 1) return pt;
  if (k == 2) return 4095 - p;
  return 4095 - pt;
}
__device__ __forceinline__ int dir_pix(int k, int l) { return inv_dir(k, l); }

// ---------------- bf16 MFMA GEMM: 64xTN tile, BK=64, XOR-swizzled LDS ----------------
template <int EPI, int TN>
__global__ __launch_bounds__(256) void k_gemm_mfma(const __hip_bfloat16* __restrict__ A,
                                                   const __hip_bfloat16* __restrict__ Bt,
                                                   const float* __restrict__ Res,
                                                   float* __restrict__ Co,
                                                   __hip_bfloat16* __restrict__ CoB,
                                                   __hip_bfloat16* __restrict__ Co2B,
                                                   float* __restrict__ dtsS,
                                                   float* __restrict__ BCs,
                                                   int M, int N, int Kk) {
  constexpr int NI = TN / 32;
  __shared__ __align__(16) short As[64 * 64];
  __shared__ __align__(16) short Bs[TN * 64];
  int tid = threadIdx.x;
  int wave = tid >> 6, lane = tid & 63;
  int mlane = lane & 15, quad = lane >> 4;
  int row0 = blockIdx.y * 64, col0 = blockIdx.x * TN;
  int wr = wave & 1, wc = wave >> 1;
  floatx4 acc[2][NI];
  #pragma unroll
  for (int mi = 0; mi < 2; mi++)
    #pragma unroll
    for (int ni = 0; ni < NI; ni++) acc[mi][ni] = (floatx4){0.f, 0.f, 0.f, 0.f};

  for (int k0 = 0; k0 < Kk; k0 += 64) {
    #pragma unroll
    for (int c = tid; c < 512; c += 256) {
      int r = c >> 3, j = c & 7;
      *(float4*)&As[r * 64 + ((j ^ (r & 7)) << 3)] =
          *(const float4*)&A[(long)(row0 + r) * Kk + k0 + j * 8];
    }
    #pragma unroll
    for (int c = tid; c < TN * 8; c += 256) {
      int r = c >> 3, j = c & 7;
      *(float4*)&Bs[r * 64 + ((j ^ (r & 7)) << 3)] =
          *(const float4*)&Bt[(long)(col0 + r) * Kk + k0 + j * 8];
    }
    __syncthreads();
    short8 af[2][2], bf[NI][2];
    #pragma unroll
    for (int mi = 0; mi < 2; mi++) {
      int r = wr * 32 + mi * 16 + mlane;
      #pragma unroll
      for (int kk = 0; kk < 2; kk++) {
        int jx = (kk * 4 + quad) ^ (r & 7);
        af[mi][kk] = *(const short8*)&As[r * 64 + jx * 8];
      }
    }
    #pragma unroll
    for (int ni = 0; ni < NI; ni++) {
      int rn = wc * (TN / 2) + ni * 16 + mlane;
      #pragma unroll
      for (int kk = 0; kk < 2; kk++) {
        int jx = (kk * 4 + quad) ^ (rn & 7);
        bf[ni][kk] = *(const short8*)&Bs[rn * 64 + jx * 8];
      }
    }
    #pragma unroll
    for (int kk = 0; kk < 2; kk++)
      #pragma unroll
      for (int mi = 0; mi < 2; mi++)
        #pragma unroll
        for (int ni = 0; ni < NI; ni++)
          acc[mi][ni] = __builtin_amdgcn_mfma_f32_16x16x32_bf16(af[mi][kk], bf[ni][kk],
                                                                acc[mi][ni], 0, 0, 0);
    __syncthreads();
  }
  // C/D layout: col=lane&15, row=quad*4+reg  [m89-verified]
  #pragma unroll
  for (int mi = 0; mi < 2; mi++) {
    #pragma unroll
    for (int ni = 0; ni < NI; ni++) {
      int cc = col0 + wc * (TN / 2) + ni * 16 + mlane;
      #pragma unroll
      for (int i = 0; i < 4; i++) {
        int rr = row0 + wr * 32 + mi * 16 + quad * 4 + i;
        float v = acc[mi][ni][i];
        if (EPI == 1) {
          Co[(long)rr * N + cc] = v + Res[(long)rr * N + cc];
        } else if (EPI == 2) {
          if (cc < 384) CoB[(long)rr * 384 + cc] = __float2bfloat16(v);
          else          Co2B[(long)rr * 384 + (cc - 384)] = __float2bfloat16(v);
        } else {  // EPI == 3: pixel-order split; B at 0..15, C at 16..31 of BCs row
          if (cc < 176) {
            int k4 = (cc >= 132) ? 3 : (cc >= 88) ? 2 : (cc >= 44) ? 1 : 0;
            int c = cc - k4 * 44;
            int b = rr >> 12, p = rr & 4095;
            long lbase = ((long)((b << 2) + k4) << 12) + p;   // pixel order
            if (c < 12) dtsS[lbase * 12 + c] = v;
            else        BCs[lbase * 32 + (c - 12)] = v;
          }
        }
      }
    }
  }
}

// ---------------- depthwise 3x3 conv + bias + SiLU; 4 pixels/block; bf16 in/out ----------------
__global__ __launch_bounds__(384) void k_conv(const __hip_bfloat16* __restrict__ xbufB,
                                              const float* __restrict__ cw,
                                              const float* __restrict__ cb,
                                              __hip_bfloat16* __restrict__ xcb) {
  int blk = blockIdx.x;            // 2048: b(2) x h(64) x wgroup(16)
  int wg = blk & 15, h = (blk >> 4) & 63, b = blk >> 10;
  int w0 = wg * 4;
  int d = threadIdx.x;
  float wt[9];
  const float* wp = cw + d * 9;
  #pragma unroll
  for (int i = 0; i < 9; i++) wt[i] = wp[i];
  float bias = cb[d];
  float v[3][6];
  #pragma unroll
  for (int r = 0; r < 3; r++) {
    int hh = h + r - 1;
    bool rok = (hh >= 0) && (hh < 64);
    #pragma unroll
    for (int c = 0; c < 6; c++) {
      int ww = w0 + c - 1;
      bool ok = rok && (ww >= 0) && (ww < 64);
      v[r][c] = ok ? __bfloat162float(xbufB[((long)(b << 12) + (hh << 6) + ww) * 384 + d]) : 0.f;
    }
  }
  #pragma unroll
  for (int i = 0; i < 4; i++) {
    float acc = bias;
    #pragma unroll
    for (int r = 0; r < 3; r++)
      #pragma unroll
      for (int c = 0; c < 3; c++)
        acc += v[r][i + c] * wt[r * 3 + c];
    float sg = 1.f / (1.f + __expf(-acc));
    xcb[((long)(b << 12) + (h << 6) + (w0 + i)) * 384 + d] = __float2bfloat16(acc * sg);
  }
}

// ---------------- dt precompute: delta = softplus(dts @ dt_w^T + dt_b) -> fp16 plane ----------------
__global__ __launch_bounds__(384) void k_dt(const float* __restrict__ dtsS,
                                            const float* __restrict__ dt_w,
                                            const float* __restrict__ dt_b,
                                            __half* __restrict__ dpre) {
  int bid = blockIdx.x;
  int chunk = bid & 127, bk = bid >> 7;
  int k = bk & 3;
  int d = threadIdx.x;
  float w[12];
  const float* dwp = dt_w + ((long)(k * 384) + d) * 12;
  #pragma unroll
  for (int r = 0; r < 12; r++) w[r] = dwp[r];
  float db = dt_b[k * 384 + d];
  long base = ((long)bk << 12) + chunk * 32;
  #pragma unroll 4
  for (int t = 0; t < 32; t++) {
    const float4* dq = (const float4*)(dtsS + (base + t) * 12);
    float4 q0 = dq[0], q1 = dq[1], q2 = dq[2];
    float x = db + q0.x * w[0] + q0.y * w[1] + q0.z * w[2] + q0.w * w[3]
                 + q1.x * w[4] + q1.y * w[5] + q1.z * w[6] + q1.w * w[7]
                 + q2.x * w[8] + q2.y * w[9] + q2.z * w[10] + q2.w * w[11];
    float e = __expf(x);
    float delta = (x > 15.f) ? x : __logf(1.f + e);
    dpre[(base + t) * 384 + d] = __float2half(delta);
  }
}

// powers: pws[n] = r^(n+1), log-depth pairing
__device__ __forceinline__ void pow16(float r, float* pws) {
  pws[0] = r;
  #pragma unroll
  for (int n = 1; n < 16; n++) {
    int m = n + 1, c = (m + 1) / 2, f = m - c;
    pws[n] = pws[c - 1] * pws[f - 1];
  }
}

// ---------------- fused scan: local scan + decoupled lookback + replay ----------------
// tile = s*8 + bk (s-major). status: 0=empty, 1=partial(E,cum), 2=inclusive(H,sig).
// Tile ids handed out by atomic counter (status[1024]) -> a block only waits on tiles
// grabbed earlier => deadlock-free under partial residency.
__global__ __launch_bounds__(384) void k_scan(
    const __half* __restrict__ dpre, const float* __restrict__ BCs,
    const __hip_bfloat16* __restrict__ xcb, const float* __restrict__ A_logs,
    float* __restrict__ Epart, float* __restrict__ cumPart,
    float* __restrict__ Hincl, float* __restrict__ sigIncl,
    int* __restrict__ status, __hip_bfloat16* __restrict__ ybufB) {
  __shared__ __align__(16) float sBC[32 * 32];   // [t][0..15]=B, [16..31]=C
  __shared__ int smTile;
  int d = threadIdx.x;
  if (d == 0) smTile = atomicAdd(status + 1024, 1);
  __syncthreads();
  int tile = smTile;
  int bk = tile & 7, s = tile >> 3;
  int k = bk & 3, b = bk >> 2;
  const float* al = A_logs + ((long)(k * 384) + d) * 16;
  bool pw = true;
  float av[16];
  #pragma unroll
  for (int n = 0; n < 16; n++) {
    float a = __expf(al[n]);
    av[n] = -a;
    pw = pw && (fabsf(a - (float)(n + 1)) < 1e-3f);
  }
  // affine pixel walk: p = p0 + stride*t within a 32-step segment (all 4 directions)
  int l0 = s * 32;
  int p0 = dir_pix(k, l0);
  int stride = dir_pix(k, l0 + 1) - p0;
  long bpk = (long)bk << 12;
  long bpix = (long)(b << 12);
  const unsigned short* dpu = (const unsigned short*)dpre;
  const unsigned short* xcu = (const unsigned short*)xcb;

  float h[16];
  #pragma unroll
  for (int n = 0; n < 16; n++) h[n] = 0.f;
  float cum = 0.f;
  unsigned dpk[16], upk[16];

  // ---- loop1: local scan (E in h[], stash delta/u packed, B|C rows to LDS) ----
  if (pw) {
    #pragma unroll
    for (int t = 0; t < 32; t++) {
      int p = p0 + stride * t;
      unsigned hd = dpu[(bpk + p) * 384 + d];
      unsigned ub = xcu[(bpix + p) * 384 + d];
      if (t & 1) { dpk[t >> 1] |= hd << 16; upk[t >> 1] |= ub << 16; }
      else       { dpk[t >> 1] = hd;        upk[t >> 1] = ub; }
      float delta = __half2float(__ushort_as_half((unsigned short)hd));
      float u = __uint_as_float(ub << 16);
      cum += delta;
      float du = delta * u;
      const float4* Bq = (const float4*)(BCs + (bpk + p) * 32);
      if (d < 8) ((float4*)sBC)[t * 8 + d] = Bq[d];
      float4 b0 = Bq[0], b1 = Bq[1], b2 = Bq[2], b3 = Bq[3];
      float Bl[16] = {b0.x, b0.y, b0.z, b0.w, b1.x, b1.y, b1.z, b1.w,
                      b2.x, b2.y, b2.z, b2.w, b3.x, b3.y, b3.z, b3.w};
      float rr = __expf(-delta);
      float pws[16]; pow16(rr, pws);
      #pragma unroll
      for (int n = 0; n < 16; n++) h[n] = pws[n] * h[n] + du * Bl[n];
    }
  } else {
    #pragma unroll 4
    for (int t = 0; t < 32; t++) {
      int p = p0 + stride * t;
      float delta = __half2float(dpre[(bpk + p) * 384 + d]);
      float u = __uint_as_float((unsigned)xcu[(bpix + p) * 384 + d] << 16);
      cum += delta;
      float du = delta * u;
      const float4* Bq = (const float4*)(BCs + (bpk + p) * 32);
      if (d < 8) ((float4*)sBC)[t * 8 + d] = Bq[d];
      float4 b0 = Bq[0], b1 = Bq[1], b2 = Bq[2], b3 = Bq[3];
      float Bl[16] = {b0.x, b0.y, b0.z, b0.w, b1.x, b1.y, b1.z, b1.w,
                      b2.x, b2.y, b2.z, b2.w, b3.x, b3.y, b3.z, b3.w};
      #pragma unroll
      for (int n = 0; n < 16; n++) h[n] = __expf(delta * av[n]) * h[n] + du * Bl[n];
    }
  }

  long tb = (long)tile * 6144 + d * 16;
  // ---- publish partial ----
  if (s > 0) {
    *(float4*)&Epart[tb + 0]  = *(float4*)&h[0];
    *(float4*)&Epart[tb + 4]  = *(float4*)&h[4];
    *(float4*)&Epart[tb + 8]  = *(float4*)&h[8];
    *(float4*)&Epart[tb + 12] = *(float4*)&h[12];
    cumPart[(long)tile * 384 + d] = cum;
    __syncthreads();
    if (d == 0) __hip_atomic_store(&status[tile], 1, __ATOMIC_RELEASE, __HIP_MEMORY_SCOPE_AGENT);
  }
  // ---- lookback ----
  float hin[16];
  #pragma unroll
  for (int n = 0; n < 16; n++) hin[n] = 0.f;
  float sig_in = 0.f;
  if (s > 0) {
    float sigAcc = 0.f;
    int j = s - 1;
    while (true) {
      int jt = j * 8 + bk;
      int st;
      do {
        st = __hip_atomic_load(&status[jt], __ATOMIC_ACQUIRE, __HIP_MEMORY_SCOPE_AGENT);
        if (st == 0) __builtin_amdgcn_s_sleep(1);
      } while (st == 0);
      float fac[16];
      if (pw) { float rc = __expf(-sigAcc); pow16(rc, fac); }
      else {
        #pragma unroll
        for (int n = 0; n < 16; n++) fac[n] = __expf(av[n] * sigAcc);
      }
      long jb = (long)jt * 6144 + d * 16;
      if (st == 2) {
        float Hj[16];
        *(float4*)&Hj[0]  = *(const float4*)&Hincl[jb + 0];
        *(float4*)&Hj[4]  = *(const float4*)&Hincl[jb + 4];
        *(float4*)&Hj[8]  = *(const float4*)&Hincl[jb + 8];
        *(float4*)&Hj[12] = *(const float4*)&Hincl[jb + 12];
        #pragma unroll
        for (int n = 0; n < 16; n++) hin[n] += fac[n] * Hj[n];
        sig_in = sigAcc + sigIncl[(long)jt * 384 + d];
        break;
      } else {
        float Ej[16];
        *(float4*)&Ej[0]  = *(const float4*)&Epart[jb + 0];
        *(float4*)&Ej[4]  = *(const float4*)&Epart[jb + 4];
        *(float4*)&Ej[8]  = *(const float4*)&Epart[jb + 8];
        *(float4*)&Ej[12] = *(const float4*)&Epart[jb + 12];
        #pragma unroll
        for (int n = 0; n < 16; n++) hin[n] += fac[n] * Ej[n];
        sigAcc += cumPart[(long)jt * 384 + d];
        j--;
        if (j < 0) { sig_in = sigAcc; break; }
      }
    }
  }
  // ---- publish inclusive ----
  {
    float fac[16];
    if (pw) { float rc = __expf(-cum); pow16(rc, fac); }
    else {
      #pragma unroll
      for (int n = 0; n < 16; n++) fac[n] = __expf(av[n] * cum);
    }
    float Hi[16];
    #pragma unroll
    for (int n = 0; n < 16; n++) Hi[n] = fac[n] * hin[n] + h[n];
    *(float4*)&Hincl[tb + 0]  = *(float4*)&Hi[0];
    *(float4*)&Hincl[tb + 4]  = *(float4*)&Hi[4];
    *(float4*)&Hincl[tb + 8]  = *(float4*)&Hi[8];
    *(float4*)&Hincl[tb + 12] = *(float4*)&Hi[12];
    sigIncl[(long)tile * 384 + d] = sig_in + cum;
    __syncthreads();   // also orders sBC writes before loop2 reads
    if (d == 0) __hip_atomic_store(&status[tile], 2, __ATOMIC_RELEASE, __HIP_MEMORY_SCOPE_AGENT);
  }
  // ---- loop2: replay from h_in, emit y ----
  float h2[16];
  #pragma unroll
  for (int n = 0; n < 16; n++) h2[n] = hin[n];
  if (pw) {
    #pragma unroll
    for (int t = 0; t < 32; t++) {
      int p = p0 + stride * t;
      unsigned wd = dpk[t >> 1];
      unsigned wu = upk[t >> 1];
      unsigned short hd = (t & 1) ? (unsigned short)(wd >> 16) : (unsigned short)(wd & 0xffff);
      unsigned ub = (t & 1) ? (wu >> 16) : (wu & 0xffff);
      float delta = __half2float(__ushort_as_half(hd));
      float u = __uint_as_float(ub << 16);
      float du = delta * u;
      float rr = __expf(-delta);
      float pws[16]; pow16(rr, pws);
      const float4* Rq = (const float4*)&sBC[t * 32];
      float4 b0 = Rq[0], b1 = Rq[1], b2 = Rq[2], b3 = Rq[3];
      float4 c0 = Rq[4], c1 = Rq[5], c2 = Rq[6], c3 = Rq[7];
      float Bl[16] = {b0.x, b0.y, b0.z, b0.w, b1.x, b1.y, b1.z, b1.w,
                      b2.x, b2.y, b2.z, b2.w, b3.x, b3.y, b3.z, b3.w};
      float Cl[16] = {c0.x, c0.y, c0.z, c0.w, c1.x, c1.y, c1.z, c1.w,
                      c2.x, c2.y, c2.z, c2.w, c3.x, c3.y, c3.z, c3.w};
      float y = 0.f;
      #pragma unroll
      for (int n = 0; n < 16; n++) { h2[n] = pws[n] * h2[n] + du * Bl[n]; y += h2[n] * Cl[n]; }
      ybufB[(bpk + p) * 384 + d] = __float2bfloat16(y);
    }
  } else {
    #pragma unroll 4
    for (int t = 0; t < 32; t++) {
      int p = p0 + stride * t;
      float delta = __half2float(dpre[(bpk + p) * 384 + d]);
      float u = __uint_as_float((unsigned)xcu[(bpix + p) * 384 + d] << 16);
      float du = delta * u;
      const float4* Rq = (const float4*)&sBC[t * 32];
      float4 b0 = Rq[0], b1 = Rq[1], b2 = Rq[2], b3 = Rq[3];
      float4 c0 = Rq[4], c1 = Rq[5], c2 = Rq[6], c3 = Rq[7];
      float Bl[16] = {b0.x, b0.y, b0.z, b0.w, b1.x, b1.y, b1.z, b1.w,
                      b2.x, b2.y, b2.z, b2.w, b3.x, b3.y, b3.z, b3.w};
      float Cl[16] = {c0.x, c0.y, c0.z, c0.w, c1.x, c1.y, c1.z, c1.w,
                      c2.x, c2.y, c2.z, c2.w, c3.x, c3.y, c3.z, c3.w};
      float y = 0.f;
      #pragma unroll
      for (int n = 0; n < 16; n++) {
        float dA = __expf(delta * av[n]);
        h2[n] = dA * h2[n] + du * Bl[n];
        y += h2[n] * Cl[n];
      }
      ybufB[(bpk + p) * 384 + d] = __float2bfloat16(y);
    }
  }
}

// ---------------- merge: gather 4 y-planes + D-skip + out-LN + silu(z) -> bf16 ----------------
__global__ __launch_bounds__(384) void k_merge(const __hip_bfloat16* __restrict__ yinB,
                                               const __hip_bfloat16* __restrict__ xcb,
                                               const __hip_bfloat16* __restrict__ zbufB,
                                               const float* __restrict__ Ds,
                                               const float* __restrict__ g,
                                               const float* __restrict__ be,
                                               __hip_bfloat16* __restrict__ yactb) {
  int row = blockIdx.x;
  int d = threadIdx.x;
  int b = row >> 12, p = row & 4095;
  long base = ((long)(b << 2) << 12) + p;  // plane (b*4+k)*4096 + p
  float v = __bfloat162float(yinB[base * 384 + d])
          + __bfloat162float(yinB[(base + 4096) * 384 + d])
          + __bfloat162float(yinB[(base + 8192) * 384 + d])
          + __bfloat162float(yinB[(base + 12288) * 384 + d]);
  float sd = Ds[d] + Ds[384 + d] + Ds[768 + d] + Ds[1152 + d];
  v += __bfloat162float(xcb[(long)row * 384 + d]) * sd;
  float s1 = v, s2 = v * v;
  #pragma unroll
  for (int o = 32; o > 0; o >>= 1) { s1 += __shfl_xor(s1, o); s2 += __shfl_xor(s2, o); }
  __shared__ float r1[6], r2[6];
  int wv = threadIdx.x >> 6;
  if ((threadIdx.x & 63) == 0) { r1[wv] = s1; r2[wv] = s2; }
  __syncthreads();
  float S1 = 0.f, S2 = 0.f;
  #pragma unroll
  for (int i = 0; i < 6; i++) { S1 += r1[i]; S2 += r2[i]; }
  float mu = S1 * (1.f / 384.f);
  float var = S2 * (1.f / 384.f) - mu * mu;
  float rr = rsqrtf(var + 1e-5f);
  float yn = (v - mu) * rr * g[d] + be[d];
  float z = __bfloat162float(zbufB[(long)row * 384 + d]);
  float sg = z / (1.f + __expf(-z));
  yactb[(long)row * 384 + d] = __float2bfloat16(yn * sg);
}

extern "C" void kernel_launch(void* const* d_in, const int* in_sizes, int n_in,
                              void* d_out, int out_size, void* d_ws, size_t ws_size,
                              hipStream_t stream) {
  const float* input      = (const float*)d_in[0];
  const float* norm_g     = (const float*)d_in[1];
  const float* norm_b     = (const float*)d_in[2];
  const float* in_proj_w  = (const float*)d_in[3];
  const float* conv_w     = (const float*)d_in[4];
  const float* conv_b     = (const float*)d_in[5];
  const float* x_proj_w   = (const float*)d_in[6];
  const float* dt_w       = (const float*)d_in[7];
  const float* dt_b       = (const float*)d_in[8];
  const float* A_logs     = (const float*)d_in[9];
  const float* Ds         = (const float*)d_in[10];
  const float* out_norm_g = (const float*)d_in[11];
  const float* out_norm_b = (const float*)d_in[12];
  const float* out_proj_w = (const float*)d_in[13];
  float* out = (float*)d_out;

  float* ws = (float*)d_ws;
  long o = 0;
  __hip_bfloat16* xnb   = (__hip_bfloat16*)(ws + o); o += 786432;   // 8192x192 bf16
  __hip_bfloat16* xbufB = (__hip_bfloat16*)(ws + o); o += 1572864;  // 8192x384 bf16
  __hip_bfloat16* zbufB = (__hip_bfloat16*)(ws + o); o += 1572864;
  __hip_bfloat16* xcb   = (__hip_bfloat16*)(ws + o); o += 1572864;
  __hip_bfloat16* Wt1   = (__hip_bfloat16*)(ws + o); o += 73728;    // 768x192 bf16
  __hip_bfloat16* Wt2   = (__hip_bfloat16*)(ws + o); o += 36864;
  __hip_bfloat16* Wt3   = (__hip_bfloat16*)(ws + o); o += 36864;
  float* dtsS           = ws + o;                    o += 393216;   // (BK,p,12) pixel order
  float* BCs            = ws + o;                    o += 1048576;  // (BK,p,32): B|C interleaved
  __half* dpre          = (__half*)(ws + o);         o += 6291456;  // (BK,p,384) fp16 delta
  float* Epart          = ws + o;                    o += 6291456;  // (1024, 6144)
  float* Hincl          = ws + o;                    o += 6291456;
  float* cumPart        = ws + o;                    o += 393216;   // (1024, 384)
  float* sigIncl        = ws + o;                    o += 393216;
  int*   statusA        = (int*)(ws + o);            o += 2048;     // status[1024] + counter
  __hip_bfloat16* ybufB = (__hip_bfloat16*)(ws + o); o += 6291456;  // (BK,p,384) bf16
  __hip_bfloat16* yactb = (__hip_bfloat16*)(ws + o); o += 1572864;
  // total ~34.6M floats ~138 MB (workspace is 256 MB per fill evidence)

  hipMemsetAsync(statusA, 0, 2048 * 4, stream);
  k_ln<<<dim3(2048), dim3(256), 0, stream>>>(input, norm_g, norm_b, xnb);
  k_packw<<<dim3(1152), dim3(256), 0, stream>>>(in_proj_w, x_proj_w, out_proj_w, Wt1, Wt2, Wt3);
  k_gemm_mfma<2, 128><<<dim3(6, 128), dim3(256), 0, stream>>>(xnb, Wt1, nullptr, nullptr, xbufB, zbufB,
                                                              nullptr, nullptr, 8192, 768, 192);
  k_conv<<<dim3(2048), dim3(384), 0, stream>>>(xbufB, conv_w, conv_b, xcb);
  k_gemm_mfma<3, 64><<<dim3(3, 128), dim3(256), 0, stream>>>(xcb, Wt2, nullptr, nullptr, nullptr, nullptr,
                                                             dtsS, BCs, 8192, 192, 384);
  k_dt<<<dim3(1024), dim3(384), 0, stream>>>(dtsS, dt_w, dt_b, dpre);
  k_scan<<<dim3(1024), dim3(384), 0, stream>>>(dpre, BCs, xcb, A_logs, Epart, cumPart,
                                               Hincl, sigIncl, statusA, ybufB);
  k_merge<<<dim3(8192), dim3(384), 0, stream>>>(ybufB, xcb, zbufB, Ds, out_norm_g, out_norm_b, yactb);
  k_gemm_mfma<1, 64><<<dim3(3, 128), dim3(256), 0, stream>>>(yactb, Wt3, input, out, nullptr, nullptr,
                                                             nullptr, nullptr, 8192, 192, 384);
}

// Round 8
// 253.028 us; speedup vs baseline: 2.5950x; 2.5950x over previous
//
#include <hip/hip_runtime.h>
#include <hip/hip_bf16.h>
#include <hip/hip_fp16.h>

// VSSBlock: B=2 H=64 W=64 C=192 DM=384 N=16 R=12 K=4 L=4096
// R16: full revert of R15's fused-lookback scan (656us — 8 chains x 128 tiles serialized).
//      Base = R14 (244.2us, best verified). ONE change: T=32->64 (SEG 128->64):
//      halves Eb/Dend round-trip (R11 proved scans respond to Eb traffic, not grid size)
//      and halves k_combine work (64-wide Kogge-Stone, 1 wave/block).

typedef __attribute__((ext_vector_type(8))) short short8;     // 8 bf16 = 4 VGPRs
typedef __attribute__((ext_vector_type(4))) float floatx4;    // fp32 accum frag

// ---------------- LayerNorm (pre-norm, eps 1e-6), C=192 -> bf16 ----------------
__global__ __launch_bounds__(256) void k_ln(const float* __restrict__ in,
                                            const float* __restrict__ g,
                                            const float* __restrict__ be,
                                            __hip_bfloat16* __restrict__ out) {
  int row = blockIdx.x * 4 + (threadIdx.x >> 6);
  int lane = threadIdx.x & 63;
  const float* x = in + (long)row * 192;
  float v0 = x[lane], v1 = x[lane + 64], v2 = x[lane + 128];
  float s = v0 + v1 + v2;
  float s2 = v0 * v0 + v1 * v1 + v2 * v2;
  #pragma unroll
  for (int o = 32; o > 0; o >>= 1) { s += __shfl_xor(s, o); s2 += __shfl_xor(s2, o); }
  float mu = s * (1.f / 192.f);
  float var = s2 * (1.f / 192.f) - mu * mu;
  float r = rsqrtf(var + 1e-6f);
  __hip_bfloat16* op = out + (long)row * 192;
  op[lane]       = __float2bfloat16((v0 - mu) * r * g[lane]       + be[lane]);
  op[lane + 64]  = __float2bfloat16((v1 - mu) * r * g[lane + 64]  + be[lane + 64]);
  op[lane + 128] = __float2bfloat16((v2 - mu) * r * g[lane + 128] + be[lane + 128]);
}

// ---------------- pack weights -> bf16, transposed to (N x K) ----------------
__global__ __launch_bounds__(256) void k_packw(const float* __restrict__ ipw,
                                               const float* __restrict__ xpw,
                                               const float* __restrict__ opw,
                                               __hip_bfloat16* __restrict__ Wt1,
                                               __hip_bfloat16* __restrict__ Wt2,
                                               __hip_bfloat16* __restrict__ Wt3) {
  int idx = blockIdx.x * 256 + threadIdx.x;
  if (idx < 147456) {                       // Wt1[n][k] = ipw[k][n]
    int n = idx / 192, k = idx - n * 192;
    Wt1[idx] = __float2bfloat16(ipw[(long)k * 768 + n]);
  } else if (idx < 147456 + 73728) {        // Wt2[j][d]
    int t = idx - 147456;
    int j = t / 384;
    float v = (j < 176) ? xpw[t] : 0.f;
    Wt2[t] = __float2bfloat16(v);
  } else if (idx < 147456 + 73728 + 73728) {// Wt3[n][k] = opw[k][n]
    int t = idx - 147456 - 73728;
    int n = t / 384, k = t - n * 384;
    Wt3[t] = __float2bfloat16(opw[(long)k * 192 + n]);
  }
}

// direction map (involutions): pixel p <-> scan position l
__device__ __forceinline__ int inv_dir(int k, int p) {
  int pt = ((p & 63) << 6) | (p >> 6);
  if (k == 0) return p;
  if (k == 1) return pt;
  if (k == 2) return 4095 - p;
  return 4095 - pt;
}
__device__ __forceinline__ int dir_pix(int k, int l) { return inv_dir(k, l); }

// ---------------- bf16 MFMA GEMM: 64xTN tile, BK=64, XOR-swizzled LDS ----------------
template <int EPI, int TN>
__global__ __launch_bounds__(256) void k_gemm_mfma(const __hip_bfloat16* __restrict__ A,
                                                   const __hip_bfloat16* __restrict__ Bt,
                                                   const float* __restrict__ Res,
                                                   float* __restrict__ Co,
                                                   __hip_bfloat16* __restrict__ CoB,
                                                   __hip_bfloat16* __restrict__ Co2B,
                                                   float* __restrict__ dtsS,
                                                   float* __restrict__ BCs,
                                                   int M, int N, int Kk) {
  constexpr int NI = TN / 32;
  __shared__ __align__(16) short As[64 * 64];
  __shared__ __align__(16) short Bs[TN * 64];
  int tid = threadIdx.x;
  int wave = tid >> 6, lane = tid & 63;
  int mlane = lane & 15, quad = lane >> 4;
  int row0 = blockIdx.y * 64, col0 = blockIdx.x * TN;
  int wr = wave & 1, wc = wave >> 1;
  floatx4 acc[2][NI];
  #pragma unroll
  for (int mi = 0; mi < 2; mi++)
    #pragma unroll
    for (int ni = 0; ni < NI; ni++) acc[mi][ni] = (floatx4){0.f, 0.f, 0.f, 0.f};

  for (int k0 = 0; k0 < Kk; k0 += 64) {
    #pragma unroll
    for (int c = tid; c < 512; c += 256) {
      int r = c >> 3, j = c & 7;
      *(float4*)&As[r * 64 + ((j ^ (r & 7)) << 3)] =
          *(const float4*)&A[(long)(row0 + r) * Kk + k0 + j * 8];
    }
    #pragma unroll
    for (int c = tid; c < TN * 8; c += 256) {
      int r = c >> 3, j = c & 7;
      *(float4*)&Bs[r * 64 + ((j ^ (r & 7)) << 3)] =
          *(const float4*)&Bt[(long)(col0 + r) * Kk + k0 + j * 8];
    }
    __syncthreads();
    short8 af[2][2], bf[NI][2];
    #pragma unroll
    for (int mi = 0; mi < 2; mi++) {
      int r = wr * 32 + mi * 16 + mlane;
      #pragma unroll
      for (int kk = 0; kk < 2; kk++) {
        int jx = (kk * 4 + quad) ^ (r & 7);
        af[mi][kk] = *(const short8*)&As[r * 64 + jx * 8];
      }
    }
    #pragma unroll
    for (int ni = 0; ni < NI; ni++) {
      int rn = wc * (TN / 2) + ni * 16 + mlane;
      #pragma unroll
      for (int kk = 0; kk < 2; kk++) {
        int jx = (kk * 4 + quad) ^ (rn & 7);
        bf[ni][kk] = *(const short8*)&Bs[rn * 64 + jx * 8];
      }
    }
    #pragma unroll
    for (int kk = 0; kk < 2; kk++)
      #pragma unroll
      for (int mi = 0; mi < 2; mi++)
        #pragma unroll
        for (int ni = 0; ni < NI; ni++)
          acc[mi][ni] = __builtin_amdgcn_mfma_f32_16x16x32_bf16(af[mi][kk], bf[ni][kk],
                                                                acc[mi][ni], 0, 0, 0);
    __syncthreads();
  }
  // C/D layout: col=lane&15, row=quad*4+reg  [m89-verified]
  #pragma unroll
  for (int mi = 0; mi < 2; mi++) {
    #pragma unroll
    for (int ni = 0; ni < NI; ni++) {
      int cc = col0 + wc * (TN / 2) + ni * 16 + mlane;
      #pragma unroll
      for (int i = 0; i < 4; i++) {
        int rr = row0 + wr * 32 + mi * 16 + quad * 4 + i;
        float v = acc[mi][ni][i];
        if (EPI == 1) {
          Co[(long)rr * N + cc] = v + Res[(long)rr * N + cc];
        } else if (EPI == 2) {
          if (cc < 384) CoB[(long)rr * 384 + cc] = __float2bfloat16(v);
          else          Co2B[(long)rr * 384 + (cc - 384)] = __float2bfloat16(v);
        } else {  // EPI == 3: pixel-order split; B at 0..15, C at 16..31 of BCs row
          if (cc < 176) {
            int k4 = (cc >= 132) ? 3 : (cc >= 88) ? 2 : (cc >= 44) ? 1 : 0;
            int c = cc - k4 * 44;
            int b = rr >> 12, p = rr & 4095;
            long lbase = ((long)((b << 2) + k4) << 12) + p;   // pixel order
            if (c < 12) dtsS[lbase * 12 + c] = v;
            else        BCs[lbase * 32 + (c - 12)] = v;
          }
        }
      }
    }
  }
}

// ---------------- depthwise 3x3 conv + bias + SiLU; 4 pixels/block; bf16 in/out ----------------
__global__ __launch_bounds__(384) void k_conv(const __hip_bfloat16* __restrict__ xbufB,
                                              const float* __restrict__ cw,
                                              const float* __restrict__ cb,
                                              __hip_bfloat16* __restrict__ xcb) {
  int blk = blockIdx.x;            // 2048: b(2) x h(64) x wgroup(16)
  int wg = blk & 15, h = (blk >> 4) & 63, b = blk >> 10;
  int w0 = wg * 4;
  int d = threadIdx.x;
  float wt[9];
  const float* wp = cw + d * 9;
  #pragma unroll
  for (int i = 0; i < 9; i++) wt[i] = wp[i];
  float bias = cb[d];
  float v[3][6];
  #pragma unroll
  for (int r = 0; r < 3; r++) {
    int hh = h + r - 1;
    bool rok = (hh >= 0) && (hh < 64);
    #pragma unroll
    for (int c = 0; c < 6; c++) {
      int ww = w0 + c - 1;
      bool ok = rok && (ww >= 0) && (ww < 64);
      v[r][c] = ok ? __bfloat162float(xbufB[((long)(b << 12) + (hh << 6) + ww) * 384 + d]) : 0.f;
    }
  }
  #pragma unroll
  for (int i = 0; i < 4; i++) {
    float acc = bias;
    #pragma unroll
    for (int r = 0; r < 3; r++)
      #pragma unroll
      for (int c = 0; c < 3; c++)
        acc += v[r][i + c] * wt[r * 3 + c];
    float sg = 1.f / (1.f + __expf(-acc));
    xcb[((long)(b << 12) + (h << 6) + (w0 + i)) * 384 + d] = __float2bfloat16(acc * sg);
  }
}

// ---------------- dt precompute: delta = softplus(dts @ dt_w^T + dt_b) -> fp16 plane ----------------
__global__ __launch_bounds__(384) void k_dt(const float* __restrict__ dtsS,
                                            const float* __restrict__ dt_w,
                                            const float* __restrict__ dt_b,
                                            __half* __restrict__ dpre) {
  int bid = blockIdx.x;
  int chunk = bid & 127, bk = bid >> 7;
  int k = bk & 3;
  int d = threadIdx.x;
  float w[12];
  const float* dwp = dt_w + ((long)(k * 384) + d) * 12;
  #pragma unroll
  for (int r = 0; r < 12; r++) w[r] = dwp[r];
  float db = dt_b[k * 384 + d];
  long base = ((long)bk << 12) + chunk * 32;
  #pragma unroll 4
  for (int t = 0; t < 32; t++) {
    const float4* dq = (const float4*)(dtsS + (base + t) * 12);
    float4 q0 = dq[0], q1 = dq[1], q2 = dq[2];
    float x = db + q0.x * w[0] + q0.y * w[1] + q0.z * w[2] + q0.w * w[3]
                 + q1.x * w[4] + q1.y * w[5] + q1.z * w[6] + q1.w * w[7]
                 + q2.x * w[8] + q2.y * w[9] + q2.z * w[10] + q2.w * w[11];
    float e = __expf(x);
    float delta = (x > 15.f) ? x : __logf(1.f + e);
    dpre[(base + t) * 384 + d] = __float2half(delta);
  }
}

// powers: pws[n] = r^(n+1), log-depth pairing
__device__ __forceinline__ void pow16(float r, float* pws) {
  pws[0] = r;
  #pragma unroll
  for (int n = 1; n < 16; n++) {
    int m = n + 1, c = (m + 1) / 2, f = m - c;
    pws[n] = pws[c - 1] * pws[f - 1];
  }
}

// ---------------- scan pass 0: SEG segments x T steps; E[16] + scalar cumDelta ----------------
template <int T>
__global__ __launch_bounds__(384) void k_scan0(
    const __half* __restrict__ dpre, const float* __restrict__ BCs,
    const __hip_bfloat16* __restrict__ xcb,
    const float* __restrict__ A_logs,
    float* __restrict__ Eb, float* __restrict__ Dend) {
  constexpr int SEG = 4096 / T;
  int bid = blockIdx.x;
  int s = bid & (SEG - 1), bk = bid / SEG;
  int k = bk & 3, b = bk >> 2;
  int d = threadIdx.x;
  const float* al = A_logs + ((long)(k * 384) + d) * 16;
  bool pw = true;
  float av[16];
  #pragma unroll
  for (int n = 0; n < 16; n++) {
    float a = __expf(al[n]);
    av[n] = -a;
    pw = pw && (fabsf(a - (float)(n + 1)) < 1e-3f);
  }
  float h[16];
  #pragma unroll
  for (int n = 0; n < 16; n++) h[n] = 0.f;
  float cum = 0.f;
  long bpk = (long)bk << 12;
  long bpix = (long)(b << 12);

  if (pw) {
    #pragma unroll 4
    for (int t = 0; t < T; t++) {
      int p = dir_pix(k, s * T + t);
      float delta = __half2float(dpre[(bpk + p) * 384 + d]);
      float u = __bfloat162float(xcb[(bpix + p) * 384 + d]);
      cum += delta;
      float du = delta * u;
      float rr = __expf(-delta);
      float pws[16]; pow16(rr, pws);
      const float4* Bq = (const float4*)(BCs + (bpk + p) * 32);
      float4 b0 = Bq[0], b1 = Bq[1], b2 = Bq[2], b3 = Bq[3];
      float Bl[16] = {b0.x, b0.y, b0.z, b0.w, b1.x, b1.y, b1.z, b1.w,
                      b2.x, b2.y, b2.z, b2.w, b3.x, b3.y, b3.z, b3.w};
      #pragma unroll
      for (int n = 0; n < 16; n++) h[n] = pws[n] * h[n] + du * Bl[n];
    }
  } else {
    for (int t = 0; t < T; t++) {
      int p = dir_pix(k, s * T + t);
      float delta = __half2float(dpre[(bpk + p) * 384 + d]);
      float u = __bfloat162float(xcb[(bpix + p) * 384 + d]);
      cum += delta;
      float du = delta * u;
      const float4* Bq = (const float4*)(BCs + (bpk + p) * 32);
      float4 b0 = Bq[0], b1 = Bq[1], b2 = Bq[2], b3 = Bq[3];
      float Bl[16] = {b0.x, b0.y, b0.z, b0.w, b1.x, b1.y, b1.z, b1.w,
                      b2.x, b2.y, b2.z, b2.w, b3.x, b3.y, b3.z, b3.w};
      #pragma unroll
      for (int n = 0; n < 16; n++) {
        float dA = __expf(delta * av[n]);
        h[n] = dA * h[n] + du * Bl[n];
      }
    }
  }
  long g = (long)bk * SEG + s;
  float* Ep = Eb + g * 6144 + d * 16;
  #pragma unroll
  for (int n = 0; n < 16; n++) Ep[n] = h[n];
  Dend[g * 384 + d] = cum;
}

// ---------------- combine: Kogge-Stone over SEG segments; pow16 trick ----------------
template <int SEG>
__global__ __launch_bounds__(SEG) void k_combine(float* __restrict__ Eb,
                                                 const float* __restrict__ Dend,
                                                 const float* __restrict__ A_logs) {
  int bid = blockIdx.x;            // bk*384 + d, 3072 blocks
  int bk = bid / 384;
  int d = bid - bk * 384;
  int k = bk & 3;
  int s = threadIdx.x;             // segment 0..SEG-1
  const float* al = A_logs + ((long)(k * 384) + d) * 16;
  bool pw = true;
  float av[16];
  #pragma unroll
  for (int n = 0; n < 16; n++) {
    float a = __expf(al[n]);
    av[n] = -a;
    pw = pw && (fabsf(a - (float)(n + 1)) < 1e-3f);
  }

  long ebase = ((long)bk * SEG + s) * 6144 + d * 16;
  float e[16];
  *(float4*)&e[0]  = *(const float4*)&Eb[ebase + 0];
  *(float4*)&e[4]  = *(const float4*)&Eb[ebase + 4];
  *(float4*)&e[8]  = *(const float4*)&Eb[ebase + 8];
  *(float4*)&e[12] = *(const float4*)&Eb[ebase + 12];
  float sig = Dend[((long)bk * SEG + s) * 384 + d];

  __shared__ float sE[SEG][17];    // [s][0]=sigma, [s][1..16]=e
  sE[s][0] = sig;
  #pragma unroll
  for (int n = 0; n < 16; n++) sE[s][1 + n] = e[n];
  __syncthreads();

  for (int o = 1; o < SEG; o <<= 1) {
    float ps = 0.f, pe[16];
    bool act = (s >= o);
    if (act) {
      ps = sE[s - o][0];
      #pragma unroll
      for (int n = 0; n < 16; n++) pe[n] = sE[s - o][1 + n];
    }
    __syncthreads();
    if (act) {
      if (pw) {
        float rc = __expf(-sig);
        float pwr[16]; pow16(rc, pwr);      // pwr[n] = exp(av[n]*sig), av[n]=-(n+1)
        #pragma unroll
        for (int n = 0; n < 16; n++) e[n] += pwr[n] * pe[n];
      } else {
        #pragma unroll
        for (int n = 0; n < 16; n++) e[n] += __expf(av[n] * sig) * pe[n];
      }
      sig += ps;
      sE[s][0] = sig;
      #pragma unroll
      for (int n = 0; n < 16; n++) sE[s][1 + n] = e[n];
    }
    __syncthreads();
  }

  float ho[16];
  if (s == 0) {
    #pragma unroll
    for (int n = 0; n < 16; n++) ho[n] = 0.f;
  } else {
    #pragma unroll
    for (int n = 0; n < 16; n++) ho[n] = sE[s - 1][1 + n];
  }
  *(float4*)&Eb[ebase + 0]  = *(float4*)&ho[0];
  *(float4*)&Eb[ebase + 4]  = *(float4*)&ho[4];
  *(float4*)&Eb[ebase + 8]  = *(float4*)&ho[8];
  *(float4*)&Eb[ebase + 12] = *(float4*)&ho[12];
}

// ---------------- scan pass 1: full recurrence from h_in (in Eb) ----------------
// ATOMIC=0: store y bf16 into per-direction plane ybufB. ATOMIC=1: fp32 atomicAdd ysum.
template <int T, int ATOMIC>
__global__ __launch_bounds__(384) void k_scan1(
    const __half* __restrict__ dpre, const float* __restrict__ BCs,
    const __hip_bfloat16* __restrict__ xcb,
    const float* __restrict__ A_logs, const float* __restrict__ Eb,
    __hip_bfloat16* __restrict__ ybufB, float* __restrict__ ysum) {
  constexpr int SEG = 4096 / T;
  int bid = blockIdx.x;
  int s = bid & (SEG - 1), bk = bid / SEG;
  int k = bk & 3, b = bk >> 2;
  int d = threadIdx.x;
  const float* al = A_logs + ((long)(k * 384) + d) * 16;
  bool pw = true;
  float av[16];
  #pragma unroll
  for (int n = 0; n < 16; n++) {
    float a = __expf(al[n]);
    av[n] = -a;
    pw = pw && (fabsf(a - (float)(n + 1)) < 1e-3f);
  }
  float h[16];
  const float* hp = Eb + ((long)bk * SEG + s) * 6144 + d * 16;
  #pragma unroll
  for (int n = 0; n < 16; n++) h[n] = hp[n];
  long bpk = (long)bk << 12;
  long bpix = (long)(b << 12);

  if (pw) {
    #pragma unroll 4
    for (int t = 0; t < T; t++) {
      int p = dir_pix(k, s * T + t);
      float delta = __half2float(dpre[(bpk + p) * 384 + d]);
      float u = __bfloat162float(xcb[(bpix + p) * 384 + d]);
      float du = delta * u;
      float rr = __expf(-delta);
      float pws[16]; pow16(rr, pws);
      const float4* Bq = (const float4*)(BCs + (bpk + p) * 32);
      float4 b0 = Bq[0], b1 = Bq[1], b2 = Bq[2], b3 = Bq[3];
      float Bl[16] = {b0.x, b0.y, b0.z, b0.w, b1.x, b1.y, b1.z, b1.w,
                      b2.x, b2.y, b2.z, b2.w, b3.x, b3.y, b3.z, b3.w};
      const float4* Cq = Bq + 4;
      float4 c0 = Cq[0], c1 = Cq[1], c2 = Cq[2], c3 = Cq[3];
      float Cl[16] = {c0.x, c0.y, c0.z, c0.w, c1.x, c1.y, c1.z, c1.w,
                      c2.x, c2.y, c2.z, c2.w, c3.x, c3.y, c3.z, c3.w};
      float y = 0.f;
      #pragma unroll
      for (int n = 0; n < 16; n++) { h[n] = pws[n] * h[n] + du * Bl[n]; y += h[n] * Cl[n]; }
      if (ATOMIC) atomicAdd(&ysum[(bpix + p) * 384 + d], y);
      else        ybufB[(bpk + p) * 384 + d] = __float2bfloat16(y);
    }
  } else {
    for (int t = 0; t < T; t++) {
      int p = dir_pix(k, s * T + t);
      float delta = __half2float(dpre[(bpk + p) * 384 + d]);
      float u = __bfloat162float(xcb[(bpix + p) * 384 + d]);
      float du = delta * u;
      const float4* Bq = (const float4*)(BCs + (bpk + p) * 32);
      float4 b0 = Bq[0], b1 = Bq[1], b2 = Bq[2], b3 = Bq[3];
      float Bl[16] = {b0.x, b0.y, b0.z, b0.w, b1.x, b1.y, b1.z, b1.w,
                      b2.x, b2.y, b2.z, b2.w, b3.x, b3.y, b3.z, b3.w};
      const float4* Cq = Bq + 4;
      float4 c0 = Cq[0], c1 = Cq[1], c2 = Cq[2], c3 = Cq[3];
      float Cl[16] = {c0.x, c0.y, c0.z, c0.w, c1.x, c1.y, c1.z, c1.w,
                      c2.x, c2.y, c2.z, c2.w, c3.x, c3.y, c3.z, c3.w};
      float y = 0.f;
      #pragma unroll
      for (int n = 0; n < 16; n++) {
        float dA = __expf(delta * av[n]);
        h[n] = dA * h[n] + du * Bl[n];
        y += h[n] * Cl[n];
      }
      if (ATOMIC) atomicAdd(&ysum[(bpix + p) * 384 + d], y);
      else        ybufB[(bpk + p) * 384 + d] = __float2bfloat16(y);
    }
  }
}

// ---------------- merge: y + D-skip(bf16 xcb) + out-LN + silu(z bf16) -> bf16 ----------------
template <int GATHER>
__global__ __launch_bounds__(384) void k_merge(const __hip_bfloat16* __restrict__ yinB,
                                               const float* __restrict__ yinF,
                                               const __hip_bfloat16* __restrict__ xcb,
                                               const __hip_bfloat16* __restrict__ zbufB,
                                               const float* __restrict__ Ds,
                                               const float* __restrict__ g,
                                               const float* __restrict__ be,
                                               __hip_bfloat16* __restrict__ yactb) {
  int row = blockIdx.x;
  int d = threadIdx.x;
  float v;
  if (GATHER) {
    int b = row >> 12, p = row & 4095;
    long base = ((long)(b << 2) << 12) + p;  // plane (b*4+k)*4096 + p
    v = __bfloat162float(yinB[base * 384 + d])
      + __bfloat162float(yinB[(base + 4096) * 384 + d])
      + __bfloat162float(yinB[(base + 8192) * 384 + d])
      + __bfloat162float(yinB[(base + 12288) * 384 + d]);
  } else {
    v = yinF[(long)row * 384 + d];
  }
  float sd = Ds[d] + Ds[384 + d] + Ds[768 + d] + Ds[1152 + d];
  v += __bfloat162float(xcb[(long)row * 384 + d]) * sd;
  float s1 = v, s2 = v * v;
  #pragma unroll
  for (int o = 32; o > 0; o >>= 1) { s1 += __shfl_xor(s1, o); s2 += __shfl_xor(s2, o); }
  __shared__ float r1[6], r2[6];
  int wv = threadIdx.x >> 6;
  if ((threadIdx.x & 63) == 0) { r1[wv] = s1; r2[wv] = s2; }
  __syncthreads();
  float S1 = 0.f, S2 = 0.f;
  #pragma unroll
  for (int i = 0; i < 6; i++) { S1 += r1[i]; S2 += r2[i]; }
  float mu = S1 * (1.f / 384.f);
  float var = S2 * (1.f / 384.f) - mu * mu;
  float rr = rsqrtf(var + 1e-5f);
  float yn = (v - mu) * rr * g[d] + be[d];
  float z = __bfloat162float(zbufB[(long)row * 384 + d]);
  float sg = z / (1.f + __expf(-z));
  yactb[(long)row * 384 + d] = __float2bfloat16(yn * sg);
}

extern "C" void kernel_launch(void* const* d_in, const int* in_sizes, int n_in,
                              void* d_out, int out_size, void* d_ws, size_t ws_size,
                              hipStream_t stream) {
  const float* input      = (const float*)d_in[0];
  const float* norm_g     = (const float*)d_in[1];
  const float* norm_b     = (const float*)d_in[2];
  const float* in_proj_w  = (const float*)d_in[3];
  const float* conv_w     = (const float*)d_in[4];
  const float* conv_b     = (const float*)d_in[5];
  const float* x_proj_w   = (const float*)d_in[6];
  const float* dt_w       = (const float*)d_in[7];
  const float* dt_b       = (const float*)d_in[8];
  const float* A_logs     = (const float*)d_in[9];
  const float* Ds         = (const float*)d_in[10];
  const float* out_norm_g = (const float*)d_in[11];
  const float* out_norm_b = (const float*)d_in[12];
  const float* out_proj_w = (const float*)d_in[13];
  float* out = (float*)d_out;

  // plane path total = 24,592,384 floats (~98 MB); atomic fallback = 21,446,656 (~86 MB)
  bool big = ws_size >= (size_t)24592384 * 4;

  float* ws = (float*)d_ws;
  long o = 0;
  __hip_bfloat16* xnb   = (__hip_bfloat16*)(ws + o); o += 786432;   // 8192x192 bf16
  __hip_bfloat16* xbufB = (__hip_bfloat16*)(ws + o); o += 1572864;  // 8192x384 bf16
  __hip_bfloat16* zbufB = (__hip_bfloat16*)(ws + o); o += 1572864;
  __hip_bfloat16* xcb   = (__hip_bfloat16*)(ws + o); o += 1572864;
  __hip_bfloat16* Wt1   = (__hip_bfloat16*)(ws + o); o += 73728;    // 768x192 bf16
  __hip_bfloat16* Wt2   = (__hip_bfloat16*)(ws + o); o += 36864;
  __hip_bfloat16* Wt3   = (__hip_bfloat16*)(ws + o); o += 36864;
  float* dtsS           = ws + o;                    o += 393216;   // (BK,p,12) pixel order
  float* BCs            = ws + o;                    o += 1048576;  // (BK,p,32): B|C interleaved
  __half* dpre          = (__half*)(ws + o);         o += 6291456;  // (BK,p,384) fp16 delta
  float* Eb             = ws + o;                    o += 3145728;  // (512 segs, 6144)
  float* Dend           = ws + o;                    o += 196608;   // (512, 384)
  __hip_bfloat16* ybufB = (__hip_bfloat16*)(ws + o);
  float* ysum           = ws + o;                    o += big ? 6291456 : 3145728;
  __hip_bfloat16* yactb = (__hip_bfloat16*)(ws + o); o += 1572864;

  k_ln<<<dim3(2048), dim3(256), 0, stream>>>(input, norm_g, norm_b, xnb);
  k_packw<<<dim3(1152), dim3(256), 0, stream>>>(in_proj_w, x_proj_w, out_proj_w, Wt1, Wt2, Wt3);
  k_gemm_mfma<2, 128><<<dim3(6, 128), dim3(256), 0, stream>>>(xnb, Wt1, nullptr, nullptr, xbufB, zbufB,
                                                              nullptr, nullptr, 8192, 768, 192);
  k_conv<<<dim3(2048), dim3(384), 0, stream>>>(xbufB, conv_w, conv_b, xcb);
  k_gemm_mfma<3, 64><<<dim3(3, 128), dim3(256), 0, stream>>>(xcb, Wt2, nullptr, nullptr, nullptr, nullptr,
                                                             dtsS, BCs, 8192, 192, 384);
  k_dt<<<dim3(1024), dim3(384), 0, stream>>>(dtsS, dt_w, dt_b, dpre);
  k_scan0<64><<<dim3(512), dim3(384), 0, stream>>>(dpre, BCs, xcb, A_logs, Eb, Dend);
  k_combine<64><<<dim3(3072), dim3(64), 0, stream>>>(Eb, Dend, A_logs);
  if (big) {
    k_scan1<64, 0><<<dim3(512), dim3(384), 0, stream>>>(dpre, BCs, xcb, A_logs, Eb, ybufB, nullptr);
    k_merge<1><<<dim3(8192), dim3(384), 0, stream>>>(ybufB, nullptr, xcb, zbufB, Ds,
                                                     out_norm_g, out_norm_b, yactb);
  } else {
    hipMemsetAsync(ysum, 0, (size_t)3145728 * 4, stream);
    k_scan1<64, 1><<<dim3(512), dim3(384), 0, stream>>>(dpre, BCs, xcb, A_logs, Eb, nullptr, ysum);
    k_merge<0><<<dim3(8192), dim3(384), 0, stream>>>(nullptr, ysum, xcb, zbufB, Ds,
                                                     out_norm_g, out_norm_b, yactb);
  }
  k_gemm_mfma<1, 64><<<dim3(3, 128), dim3(256), 0, stream>>>(yactb, Wt3, input, out, nullptr, nullptr,
                                                             nullptr, nullptr, 8192, 192, 384);
}

// Round 9
// 249.101 us; speedup vs baseline: 2.6359x; 1.0158x over previous
//
#include <hip/hip_runtime.h>
#include <hip/hip_bf16.h>
#include <hip/hip_fp16.h>

// VSSBlock: B=2 H=64 W=64 C=192 DM=384 N=16 R=12 K=4 L=4096
// R17: base = R14 (244.2us best; T=32/SEG=128 — R11/R16 measured T=16/64 both worse).
//      ONE change: B|C rows in scans loaded via s_load_dwordx16 (wave-uniform address
//      -> scalar loads into SGPRs) instead of 8 per-lane global_load_dwordx4/step.
//      Frees 8 VMEM issues + 32 VGPR writes per step in both scans.

typedef __attribute__((ext_vector_type(8))) short short8;     // 8 bf16 = 4 VGPRs
typedef __attribute__((ext_vector_type(4))) float floatx4;    // fp32 accum frag
typedef __attribute__((ext_vector_type(16))) float floatx16;  // 16 SGPRs (s_load_dwordx16)

// ---------------- LayerNorm (pre-norm, eps 1e-6), C=192 -> bf16 ----------------
__global__ __launch_bounds__(256) void k_ln(const float* __restrict__ in,
                                            const float* __restrict__ g,
                                            const float* __restrict__ be,
                                            __hip_bfloat16* __restrict__ out) {
  int row = blockIdx.x * 4 + (threadIdx.x >> 6);
  int lane = threadIdx.x & 63;
  const float* x = in + (long)row * 192;
  float v0 = x[lane], v1 = x[lane + 64], v2 = x[lane + 128];
  float s = v0 + v1 + v2;
  float s2 = v0 * v0 + v1 * v1 + v2 * v2;
  #pragma unroll
  for (int o = 32; o > 0; o >>= 1) { s += __shfl_xor(s, o); s2 += __shfl_xor(s2, o); }
  float mu = s * (1.f / 192.f);
  float var = s2 * (1.f / 192.f) - mu * mu;
  float r = rsqrtf(var + 1e-6f);
  __hip_bfloat16* op = out + (long)row * 192;
  op[lane]       = __float2bfloat16((v0 - mu) * r * g[lane]       + be[lane]);
  op[lane + 64]  = __float2bfloat16((v1 - mu) * r * g[lane + 64]  + be[lane + 64]);
  op[lane + 128] = __float2bfloat16((v2 - mu) * r * g[lane + 128] + be[lane + 128]);
}

// ---------------- pack weights -> bf16, transposed to (N x K) ----------------
__global__ __launch_bounds__(256) void k_packw(const float* __restrict__ ipw,
                                               const float* __restrict__ xpw,
                                               const float* __restrict__ opw,
                                               __hip_bfloat16* __restrict__ Wt1,
                                               __hip_bfloat16* __restrict__ Wt2,
                                               __hip_bfloat16* __restrict__ Wt3) {
  int idx = blockIdx.x * 256 + threadIdx.x;
  if (idx < 147456) {                       // Wt1[n][k] = ipw[k][n]
    int n = idx / 192, k = idx - n * 192;
    Wt1[idx] = __float2bfloat16(ipw[(long)k * 768 + n]);
  } else if (idx < 147456 + 73728) {        // Wt2[j][d]
    int t = idx - 147456;
    int j = t / 384;
    float v = (j < 176) ? xpw[t] : 0.f;
    Wt2[t] = __float2bfloat16(v);
  } else if (idx < 147456 + 73728 + 73728) {// Wt3[n][k] = opw[k][n]
    int t = idx - 147456 - 73728;
    int n = t / 384, k = t - n * 384;
    Wt3[t] = __float2bfloat16(opw[(long)k * 192 + n]);
  }
}

// direction map (involutions): pixel p <-> scan position l
__device__ __forceinline__ int inv_dir(int k, int p) {
  int pt = ((p & 63) << 6) | (p >> 6);
  if (k == 0) return p;
  if (k == 1) return pt;
  if (k == 2) return 4095 - p;
  return 4095 - pt;
}
__device__ __forceinline__ int dir_pix(int k, int l) { return inv_dir(k, l); }

// ---------------- bf16 MFMA GEMM: 64xTN tile, BK=64, XOR-swizzled LDS ----------------
template <int EPI, int TN>
__global__ __launch_bounds__(256) void k_gemm_mfma(const __hip_bfloat16* __restrict__ A,
                                                   const __hip_bfloat16* __restrict__ Bt,
                                                   const float* __restrict__ Res,
                                                   float* __restrict__ Co,
                                                   __hip_bfloat16* __restrict__ CoB,
                                                   __hip_bfloat16* __restrict__ Co2B,
                                                   float* __restrict__ dtsS,
                                                   float* __restrict__ BCs,
                                                   int M, int N, int Kk) {
  constexpr int NI = TN / 32;
  __shared__ __align__(16) short As[64 * 64];
  __shared__ __align__(16) short Bs[TN * 64];
  int tid = threadIdx.x;
  int wave = tid >> 6, lane = tid & 63;
  int mlane = lane & 15, quad = lane >> 4;
  int row0 = blockIdx.y * 64, col0 = blockIdx.x * TN;
  int wr = wave & 1, wc = wave >> 1;
  floatx4 acc[2][NI];
  #pragma unroll
  for (int mi = 0; mi < 2; mi++)
    #pragma unroll
    for (int ni = 0; ni < NI; ni++) acc[mi][ni] = (floatx4){0.f, 0.f, 0.f, 0.f};

  for (int k0 = 0; k0 < Kk; k0 += 64) {
    #pragma unroll
    for (int c = tid; c < 512; c += 256) {
      int r = c >> 3, j = c & 7;
      *(float4*)&As[r * 64 + ((j ^ (r & 7)) << 3)] =
          *(const float4*)&A[(long)(row0 + r) * Kk + k0 + j * 8];
    }
    #pragma unroll
    for (int c = tid; c < TN * 8; c += 256) {
      int r = c >> 3, j = c & 7;
      *(float4*)&Bs[r * 64 + ((j ^ (r & 7)) << 3)] =
          *(const float4*)&Bt[(long)(col0 + r) * Kk + k0 + j * 8];
    }
    __syncthreads();
    short8 af[2][2], bf[NI][2];
    #pragma unroll
    for (int mi = 0; mi < 2; mi++) {
      int r = wr * 32 + mi * 16 + mlane;
      #pragma unroll
      for (int kk = 0; kk < 2; kk++) {
        int jx = (kk * 4 + quad) ^ (r & 7);
        af[mi][kk] = *(const short8*)&As[r * 64 + jx * 8];
      }
    }
    #pragma unroll
    for (int ni = 0; ni < NI; ni++) {
      int rn = wc * (TN / 2) + ni * 16 + mlane;
      #pragma unroll
      for (int kk = 0; kk < 2; kk++) {
        int jx = (kk * 4 + quad) ^ (rn & 7);
        bf[ni][kk] = *(const short8*)&Bs[rn * 64 + jx * 8];
      }
    }
    #pragma unroll
    for (int kk = 0; kk < 2; kk++)
      #pragma unroll
      for (int mi = 0; mi < 2; mi++)
        #pragma unroll
        for (int ni = 0; ni < NI; ni++)
          acc[mi][ni] = __builtin_amdgcn_mfma_f32_16x16x32_bf16(af[mi][kk], bf[ni][kk],
                                                                acc[mi][ni], 0, 0, 0);
    __syncthreads();
  }
  // C/D layout: col=lane&15, row=quad*4+reg  [m89-verified]
  #pragma unroll
  for (int mi = 0; mi < 2; mi++) {
    #pragma unroll
    for (int ni = 0; ni < NI; ni++) {
      int cc = col0 + wc * (TN / 2) + ni * 16 + mlane;
      #pragma unroll
      for (int i = 0; i < 4; i++) {
        int rr = row0 + wr * 32 + mi * 16 + quad * 4 + i;
        float v = acc[mi][ni][i];
        if (EPI == 1) {
          Co[(long)rr * N + cc] = v + Res[(long)rr * N + cc];
        } else if (EPI == 2) {
          if (cc < 384) CoB[(long)rr * 384 + cc] = __float2bfloat16(v);
          else          Co2B[(long)rr * 384 + (cc - 384)] = __float2bfloat16(v);
        } else {  // EPI == 3: pixel-order split; B at 0..15, C at 16..31 of BCs row
          if (cc < 176) {
            int k4 = (cc >= 132) ? 3 : (cc >= 88) ? 2 : (cc >= 44) ? 1 : 0;
            int c = cc - k4 * 44;
            int b = rr >> 12, p = rr & 4095;
            long lbase = ((long)((b << 2) + k4) << 12) + p;   // pixel order
            if (c < 12) dtsS[lbase * 12 + c] = v;
            else        BCs[lbase * 32 + (c - 12)] = v;
          }
        }
      }
    }
  }
}

// ---------------- depthwise 3x3 conv + bias + SiLU; 4 pixels/block; bf16 in/out ----------------
__global__ __launch_bounds__(384) void k_conv(const __hip_bfloat16* __restrict__ xbufB,
                                              const float* __restrict__ cw,
                                              const float* __restrict__ cb,
                                              __hip_bfloat16* __restrict__ xcb) {
  int blk = blockIdx.x;            // 2048: b(2) x h(64) x wgroup(16)
  int wg = blk & 15, h = (blk >> 4) & 63, b = blk >> 10;
  int w0 = wg * 4;
  int d = threadIdx.x;
  float wt[9];
  const float* wp = cw + d * 9;
  #pragma unroll
  for (int i = 0; i < 9; i++) wt[i] = wp[i];
  float bias = cb[d];
  float v[3][6];
  #pragma unroll
  for (int r = 0; r < 3; r++) {
    int hh = h + r - 1;
    bool rok = (hh >= 0) && (hh < 64);
    #pragma unroll
    for (int c = 0; c < 6; c++) {
      int ww = w0 + c - 1;
      bool ok = rok && (ww >= 0) && (ww < 64);
      v[r][c] = ok ? __bfloat162float(xbufB[((long)(b << 12) + (hh << 6) + ww) * 384 + d]) : 0.f;
    }
  }
  #pragma unroll
  for (int i = 0; i < 4; i++) {
    float acc = bias;
    #pragma unroll
    for (int r = 0; r < 3; r++)
      #pragma unroll
      for (int c = 0; c < 3; c++)
        acc += v[r][i + c] * wt[r * 3 + c];
    float sg = 1.f / (1.f + __expf(-acc));
    xcb[((long)(b << 12) + (h << 6) + (w0 + i)) * 384 + d] = __float2bfloat16(acc * sg);
  }
}

// ---------------- dt precompute: delta = softplus(dts @ dt_w^T + dt_b) -> fp16 plane ----------------
__global__ __launch_bounds__(384) void k_dt(const float* __restrict__ dtsS,
                                            const float* __restrict__ dt_w,
                                            const float* __restrict__ dt_b,
                                            __half* __restrict__ dpre) {
  int bid = blockIdx.x;
  int chunk = bid & 127, bk = bid >> 7;
  int k = bk & 3;
  int d = threadIdx.x;
  float w[12];
  const float* dwp = dt_w + ((long)(k * 384) + d) * 12;
  #pragma unroll
  for (int r = 0; r < 12; r++) w[r] = dwp[r];
  float db = dt_b[k * 384 + d];
  long base = ((long)bk << 12) + chunk * 32;
  #pragma unroll 4
  for (int t = 0; t < 32; t++) {
    const float4* dq = (const float4*)(dtsS + (base + t) * 12);
    float4 q0 = dq[0], q1 = dq[1], q2 = dq[2];
    float x = db + q0.x * w[0] + q0.y * w[1] + q0.z * w[2] + q0.w * w[3]
                 + q1.x * w[4] + q1.y * w[5] + q1.z * w[6] + q1.w * w[7]
                 + q2.x * w[8] + q2.y * w[9] + q2.z * w[10] + q2.w * w[11];
    float e = __expf(x);
    float delta = (x > 15.f) ? x : __logf(1.f + e);
    dpre[(base + t) * 384 + d] = __float2half(delta);
  }
}

// powers: pws[n] = r^(n+1), log-depth pairing
__device__ __forceinline__ void pow16(float r, float* pws) {
  pws[0] = r;
  #pragma unroll
  for (int n = 1; n < 16; n++) {
    int m = n + 1, c = (m + 1) / 2, f = m - c;
    pws[n] = pws[c - 1] * pws[f - 1];
  }
}

// ---------------- scan pass 0: 128 segments x 32 steps; scalar B loads ----------------
__global__ __launch_bounds__(384) void k_scan0(
    const __half* __restrict__ dpre, const float* __restrict__ BCs,
    const __hip_bfloat16* __restrict__ xcb,
    const float* __restrict__ A_logs,
    float* __restrict__ Eb, float* __restrict__ Dend) {
  int bid = blockIdx.x;
  int s = bid & 127, bk = bid >> 7;
  int k = bk & 3, b = bk >> 2;
  int d = threadIdx.x;
  const float* al = A_logs + ((long)(k * 384) + d) * 16;
  bool pw = true;
  float av[16];
  #pragma unroll
  for (int n = 0; n < 16; n++) {
    float a = __expf(al[n]);
    av[n] = -a;
    pw = pw && (fabsf(a - (float)(n + 1)) < 1e-3f);
  }
  float h[16];
  #pragma unroll
  for (int n = 0; n < 16; n++) h[n] = 0.f;
  float cum = 0.f;
  long bpk = (long)bk << 12;
  long bpix = (long)(b << 12);

  if (pw) {
    #pragma unroll 4
    for (int t = 0; t < 32; t++) {
      int p = dir_pix(k, s * 32 + t);
      float delta = __half2float(dpre[(bpk + p) * 384 + d]);
      float u = __bfloat162float(xcb[(bpix + p) * 384 + d]);
      cum += delta;
      float du = delta * u;
      float rr = __expf(-delta);
      float pws[16]; pow16(rr, pws);
      floatx16 BV;   // wave-uniform address -> scalar load into 16 SGPRs
      asm volatile("s_load_dwordx16 %0, %1, 0x0\n\t"
                   "s_waitcnt lgkmcnt(0)"
                   : "=s"(BV) : "s"(BCs + (bpk + p) * 32));
      #pragma unroll
      for (int n = 0; n < 16; n++) h[n] = pws[n] * h[n] + du * BV[n];
    }
  } else {
    for (int t = 0; t < 32; t++) {
      int p = dir_pix(k, s * 32 + t);
      float delta = __half2float(dpre[(bpk + p) * 384 + d]);
      float u = __bfloat162float(xcb[(bpix + p) * 384 + d]);
      cum += delta;
      float du = delta * u;
      const float4* Bq = (const float4*)(BCs + (bpk + p) * 32);
      float4 b0 = Bq[0], b1 = Bq[1], b2 = Bq[2], b3 = Bq[3];
      float Bl[16] = {b0.x, b0.y, b0.z, b0.w, b1.x, b1.y, b1.z, b1.w,
                      b2.x, b2.y, b2.z, b2.w, b3.x, b3.y, b3.z, b3.w};
      #pragma unroll
      for (int n = 0; n < 16; n++) {
        float dA = __expf(delta * av[n]);
        h[n] = dA * h[n] + du * Bl[n];
      }
    }
  }
  long g = (long)bk * 128 + s;
  float* Ep = Eb + g * 6144 + d * 16;
  #pragma unroll
  for (int n = 0; n < 16; n++) Ep[n] = h[n];
  Dend[g * 384 + d] = cum;
}

// ---------------- combine: Kogge-Stone over 128 segments; pow16 trick ----------------
__global__ __launch_bounds__(128) void k_combine(float* __restrict__ Eb,
                                                 const float* __restrict__ Dend,
                                                 const float* __restrict__ A_logs) {
  int bid = blockIdx.x;            // bk*384 + d, 3072 blocks
  int bk = bid / 384;
  int d = bid - bk * 384;
  int k = bk & 3;
  int s = threadIdx.x;             // segment 0..127
  const float* al = A_logs + ((long)(k * 384) + d) * 16;
  bool pw = true;
  float av[16];
  #pragma unroll
  for (int n = 0; n < 16; n++) {
    float a = __expf(al[n]);
    av[n] = -a;
    pw = pw && (fabsf(a - (float)(n + 1)) < 1e-3f);
  }

  long ebase = ((long)bk * 128 + s) * 6144 + d * 16;
  float e[16];
  *(float4*)&e[0]  = *(const float4*)&Eb[ebase + 0];
  *(float4*)&e[4]  = *(const float4*)&Eb[ebase + 4];
  *(float4*)&e[8]  = *(const float4*)&Eb[ebase + 8];
  *(float4*)&e[12] = *(const float4*)&Eb[ebase + 12];
  float sig = Dend[((long)bk * 128 + s) * 384 + d];

  __shared__ float sE[128][17];    // [s][0]=sigma, [s][1..16]=e
  sE[s][0] = sig;
  #pragma unroll
  for (int n = 0; n < 16; n++) sE[s][1 + n] = e[n];
  __syncthreads();

  for (int o = 1; o < 128; o <<= 1) {
    float ps = 0.f, pe[16];
    bool act = (s >= o);
    if (act) {
      ps = sE[s - o][0];
      #pragma unroll
      for (int n = 0; n < 16; n++) pe[n] = sE[s - o][1 + n];
    }
    __syncthreads();
    if (act) {
      if (pw) {
        float rc = __expf(-sig);
        float pwr[16]; pow16(rc, pwr);      // pwr[n] = exp(av[n]*sig), av[n]=-(n+1)
        #pragma unroll
        for (int n = 0; n < 16; n++) e[n] += pwr[n] * pe[n];
      } else {
        #pragma unroll
        for (int n = 0; n < 16; n++) e[n] += __expf(av[n] * sig) * pe[n];
      }
      sig += ps;
      sE[s][0] = sig;
      #pragma unroll
      for (int n = 0; n < 16; n++) sE[s][1 + n] = e[n];
    }
    __syncthreads();
  }

  float ho[16];
  if (s == 0) {
    #pragma unroll
    for (int n = 0; n < 16; n++) ho[n] = 0.f;
  } else {
    #pragma unroll
    for (int n = 0; n < 16; n++) ho[n] = sE[s - 1][1 + n];
  }
  *(float4*)&Eb[ebase + 0]  = *(float4*)&ho[0];
  *(float4*)&Eb[ebase + 4]  = *(float4*)&ho[4];
  *(float4*)&Eb[ebase + 8]  = *(float4*)&ho[8];
  *(float4*)&Eb[ebase + 12] = *(float4*)&ho[12];
}

// ---------------- scan pass 1: full recurrence from h_in; scalar B|C loads ----------------
// ATOMIC=0: store y bf16 into per-direction plane ybufB. ATOMIC=1: fp32 atomicAdd ysum.
template <int ATOMIC>
__global__ __launch_bounds__(384) void k_scan1(
    const __half* __restrict__ dpre, const float* __restrict__ BCs,
    const __hip_bfloat16* __restrict__ xcb,
    const float* __restrict__ A_logs, const float* __restrict__ Eb,
    __hip_bfloat16* __restrict__ ybufB, float* __restrict__ ysum) {
  int bid = blockIdx.x;
  int s = bid & 127, bk = bid >> 7;
  int k = bk & 3, b = bk >> 2;
  int d = threadIdx.x;
  const float* al = A_logs + ((long)(k * 384) + d) * 16;
  bool pw = true;
  float av[16];
  #pragma unroll
  for (int n = 0; n < 16; n++) {
    float a = __expf(al[n]);
    av[n] = -a;
    pw = pw && (fabsf(a - (float)(n + 1)) < 1e-3f);
  }
  float h[16];
  const float* hp = Eb + ((long)bk * 128 + s) * 6144 + d * 16;
  #pragma unroll
  for (int n = 0; n < 16; n++) h[n] = hp[n];
  long bpk = (long)bk << 12;
  long bpix = (long)(b << 12);

  if (pw) {
    #pragma unroll 4
    for (int t = 0; t < 32; t++) {
      int p = dir_pix(k, s * 32 + t);
      float delta = __half2float(dpre[(bpk + p) * 384 + d]);
      float u = __bfloat162float(xcb[(bpix + p) * 384 + d]);
      float du = delta * u;
      float rr = __expf(-delta);
      float pws[16]; pow16(rr, pws);
      floatx16 BV, CV;   // wave-uniform -> 2 scalar loads (B row, C row)
      asm volatile("s_load_dwordx16 %0, %2, 0x0\n\t"
                   "s_load_dwordx16 %1, %2, 0x40\n\t"
                   "s_waitcnt lgkmcnt(0)"
                   : "=s"(BV), "=s"(CV) : "s"(BCs + (bpk + p) * 32));
      float y = 0.f;
      #pragma unroll
      for (int n = 0; n < 16; n++) { h[n] = pws[n] * h[n] + du * BV[n]; y += h[n] * CV[n]; }
      if (ATOMIC) atomicAdd(&ysum[(bpix + p) * 384 + d], y);
      else        ybufB[(bpk + p) * 384 + d] = __float2bfloat16(y);
    }
  } else {
    for (int t = 0; t < 32; t++) {
      int p = dir_pix(k, s * 32 + t);
      float delta = __half2float(dpre[(bpk + p) * 384 + d]);
      float u = __bfloat162float(xcb[(bpix + p) * 384 + d]);
      float du = delta * u;
      const float4* Bq = (const float4*)(BCs + (bpk + p) * 32);
      float4 b0 = Bq[0], b1 = Bq[1], b2 = Bq[2], b3 = Bq[3];
      float Bl[16] = {b0.x, b0.y, b0.z, b0.w, b1.x, b1.y, b1.z, b1.w,
                      b2.x, b2.y, b2.z, b2.w, b3.x, b3.y, b3.z, b3.w};
      const float4* Cq = Bq + 4;
      float4 c0 = Cq[0], c1 = Cq[1], c2 = Cq[2], c3 = Cq[3];
      float Cl[16] = {c0.x, c0.y, c0.z, c0.w, c1.x, c1.y, c1.z, c1.w,
                      c2.x, c2.y, c2.z, c2.w, c3.x, c3.y, c3.z, c3.w};
      float y = 0.f;
      #pragma unroll
      for (int n = 0; n < 16; n++) {
        float dA = __expf(delta * av[n]);
        h[n] = dA * h[n] + du * Bl[n];
        y += h[n] * Cl[n];
      }
      if (ATOMIC) atomicAdd(&ysum[(bpix + p) * 384 + d], y);
      else        ybufB[(bpk + p) * 384 + d] = __float2bfloat16(y);
    }
  }
}

// ---------------- merge: y + D-skip(bf16 xcb) + out-LN + silu(z bf16) -> bf16 ----------------
template <int GATHER>
__global__ __launch_bounds__(384) void k_merge(const __hip_bfloat16* __restrict__ yinB,
                                               const float* __restrict__ yinF,
                                               const __hip_bfloat16* __restrict__ xcb,
                                               const __hip_bfloat16* __restrict__ zbufB,
                                               const float* __restrict__ Ds,
                                               const float* __restrict__ g,
                                               const float* __restrict__ be,
                                               __hip_bfloat16* __restrict__ yactb) {
  int row = blockIdx.x;
  int d = threadIdx.x;
  float v;
  if (GATHER) {
    int b = row >> 12, p = row & 4095;
    long base = ((long)(b << 2) << 12) + p;  // plane (b*4+k)*4096 + p
    v = __bfloat162float(yinB[base * 384 + d])
      + __bfloat162float(yinB[(base + 4096) * 384 + d])
      + __bfloat162float(yinB[(base + 8192) * 384 + d])
      + __bfloat162float(yinB[(base + 12288) * 384 + d]);
  } else {
    v = yinF[(long)row * 384 + d];
  }
  float sd = Ds[d] + Ds[384 + d] + Ds[768 + d] + Ds[1152 + d];
  v += __bfloat162float(xcb[(long)row * 384 + d]) * sd;
  float s1 = v, s2 = v * v;
  #pragma unroll
  for (int o = 32; o > 0; o >>= 1) { s1 += __shfl_xor(s1, o); s2 += __shfl_xor(s2, o); }
  __shared__ float r1[6], r2[6];
  int wv = threadIdx.x >> 6;
  if ((threadIdx.x & 63) == 0) { r1[wv] = s1; r2[wv] = s2; }
  __syncthreads();
  float S1 = 0.f, S2 = 0.f;
  #pragma unroll
  for (int i = 0; i < 6; i++) { S1 += r1[i]; S2 += r2[i]; }
  float mu = S1 * (1.f / 384.f);
  float var = S2 * (1.f / 384.f) - mu * mu;
  float rr = rsqrtf(var + 1e-5f);
  float yn = (v - mu) * rr * g[d] + be[d];
  float z = __bfloat162float(zbufB[(long)row * 384 + d]);
  float sg = z / (1.f + __expf(-z));
  yactb[(long)row * 384 + d] = __float2bfloat16(yn * sg);
}

extern "C" void kernel_launch(void* const* d_in, const int* in_sizes, int n_in,
                              void* d_out, int out_size, void* d_ws, size_t ws_size,
                              hipStream_t stream) {
  const float* input      = (const float*)d_in[0];
  const float* norm_g     = (const float*)d_in[1];
  const float* norm_b     = (const float*)d_in[2];
  const float* in_proj_w  = (const float*)d_in[3];
  const float* conv_w     = (const float*)d_in[4];
  const float* conv_b     = (const float*)d_in[5];
  const float* x_proj_w   = (const float*)d_in[6];
  const float* dt_w       = (const float*)d_in[7];
  const float* dt_b       = (const float*)d_in[8];
  const float* A_logs     = (const float*)d_in[9];
  const float* Ds         = (const float*)d_in[10];
  const float* out_norm_g = (const float*)d_in[11];
  const float* out_norm_b = (const float*)d_in[12];
  const float* out_proj_w = (const float*)d_in[13];
  float* out = (float*)d_out;

  // plane path total = 27,934,720 floats (~112 MB); atomic fallback = 24,788,992 (~99 MB)
  bool big = ws_size >= (size_t)27934720 * 4;

  float* ws = (float*)d_ws;
  long o = 0;
  __hip_bfloat16* xnb   = (__hip_bfloat16*)(ws + o); o += 786432;   // 8192x192 bf16
  __hip_bfloat16* xbufB = (__hip_bfloat16*)(ws + o); o += 1572864;  // 8192x384 bf16
  __hip_bfloat16* zbufB = (__hip_bfloat16*)(ws + o); o += 1572864;
  __hip_bfloat16* xcb   = (__hip_bfloat16*)(ws + o); o += 1572864;
  __hip_bfloat16* Wt1   = (__hip_bfloat16*)(ws + o); o += 73728;    // 768x192 bf16
  __hip_bfloat16* Wt2   = (__hip_bfloat16*)(ws + o); o += 36864;
  __hip_bfloat16* Wt3   = (__hip_bfloat16*)(ws + o); o += 36864;
  float* dtsS           = ws + o;                    o += 393216;   // (BK,p,12) pixel order
  float* BCs            = ws + o;                    o += 1048576;  // (BK,p,32): B|C interleaved
  __half* dpre          = (__half*)(ws + o);         o += 6291456;  // (BK,p,384) fp16 delta
  float* Eb             = ws + o;                    o += 6291456;  // (1024 segs, 6144)
  float* Dend           = ws + o;                    o += 393216;   // (1024, 384)
  __hip_bfloat16* ybufB = (__hip_bfloat16*)(ws + o);
  float* ysum           = ws + o;                    o += big ? 6291456 : 3145728;
  __hip_bfloat16* yactb = (__hip_bfloat16*)(ws + o); o += 1572864;

  k_ln<<<dim3(2048), dim3(256), 0, stream>>>(input, norm_g, norm_b, xnb);
  k_packw<<<dim3(1152), dim3(256), 0, stream>>>(in_proj_w, x_proj_w, out_proj_w, Wt1, Wt2, Wt3);
  k_gemm_mfma<2, 128><<<dim3(6, 128), dim3(256), 0, stream>>>(xnb, Wt1, nullptr, nullptr, xbufB, zbufB,
                                                              nullptr, nullptr, 8192, 768, 192);
  k_conv<<<dim3(2048), dim3(384), 0, stream>>>(xbufB, conv_w, conv_b, xcb);
  k_gemm_mfma<3, 64><<<dim3(3, 128), dim3(256), 0, stream>>>(xcb, Wt2, nullptr, nullptr, nullptr, nullptr,
                                                             dtsS, BCs, 8192, 192, 384);
  k_dt<<<dim3(1024), dim3(384), 0, stream>>>(dtsS, dt_w, dt_b, dpre);
  k_scan0<<<dim3(1024), dim3(384), 0, stream>>>(dpre, BCs, xcb, A_logs, Eb, Dend);
  k_combine<<<dim3(3072), dim3(128), 0, stream>>>(Eb, Dend, A_logs);
  if (big) {
    k_scan1<0><<<dim3(1024), dim3(384), 0, stream>>>(dpre, BCs, xcb, A_logs, Eb, ybufB, nullptr);
    k_merge<1><<<dim3(8192), dim3(384), 0, stream>>>(ybufB, nullptr, xcb, zbufB, Ds,
                                                     out_norm_g, out_norm_b, yactb);
  } else {
    hipMemsetAsync(ysum, 0, (size_t)3145728 * 4, stream);
    k_scan1<1><<<dim3(1024), dim3(384), 0, stream>>>(dpre, BCs, xcb, A_logs, Eb, nullptr, ysum);
    k_merge<0><<<dim3(8192), dim3(384), 0, stream>>>(nullptr, ysum, xcb, zbufB, Ds,
                                                     out_norm_g, out_norm_b, yactb);
  }
  k_gemm_mfma<1, 64><<<dim3(3, 128), dim3(256), 0, stream>>>(yactb, Wt3, input, out, nullptr, nullptr,
                                                             nullptr, nullptr, 8192, 192, 384);
}

// Round 10
// 236.495 us; speedup vs baseline: 2.7764x; 1.0533x over previous
//
#include <hip/hip_runtime.h>
#include <hip/hip_bf16.h>
#include <hip/hip_fp16.h>

// VSSBlock: B=2 H=64 W=64 C=192 DM=384 N=16 R=12 K=4 L=4096
// R18: base = R14 (244.2us best; R17's scalar-load asm reverted — it cost 5us).
//      (1) Eb/h_in plane stored fp16 (halves the 100MB scan0->combine->scan1 round-trip;
//          combine internals fp32, Dend fp32); (2) conv tiled 2x4 (24 loads/8 outputs);
//      (3) k_ln+k_packw fused into one dispatch. Scans: T=32/SEG=128, per-lane B|C loads.

typedef __attribute__((ext_vector_type(8))) short short8;     // 8 bf16 = 4 VGPRs
typedef __attribute__((ext_vector_type(4))) float floatx4;    // fp32 accum frag

// ---------------- fused: LN (pre-norm, eps 1e-6) -> bf16  +  weight pack ----------------
__global__ __launch_bounds__(256) void k_lnpackw(const float* __restrict__ in,
                                                 const float* __restrict__ g,
                                                 const float* __restrict__ be,
                                                 __hip_bfloat16* __restrict__ out,
                                                 const float* __restrict__ ipw,
                                                 const float* __restrict__ xpw,
                                                 const float* __restrict__ opw,
                                                 __hip_bfloat16* __restrict__ Wt1,
                                                 __hip_bfloat16* __restrict__ Wt2,
                                                 __hip_bfloat16* __restrict__ Wt3) {
  int bid = blockIdx.x;
  if (bid < 2048) {                 // LayerNorm: 4 rows/block
    int row = bid * 4 + (threadIdx.x >> 6);
    int lane = threadIdx.x & 63;
    const float* x = in + (long)row * 192;
    float v0 = x[lane], v1 = x[lane + 64], v2 = x[lane + 128];
    float s = v0 + v1 + v2;
    float s2 = v0 * v0 + v1 * v1 + v2 * v2;
    #pragma unroll
    for (int o = 32; o > 0; o >>= 1) { s += __shfl_xor(s, o); s2 += __shfl_xor(s2, o); }
    float mu = s * (1.f / 192.f);
    float var = s2 * (1.f / 192.f) - mu * mu;
    float r = rsqrtf(var + 1e-6f);
    __hip_bfloat16* op = out + (long)row * 192;
    op[lane]       = __float2bfloat16((v0 - mu) * r * g[lane]       + be[lane]);
    op[lane + 64]  = __float2bfloat16((v1 - mu) * r * g[lane + 64]  + be[lane + 64]);
    op[lane + 128] = __float2bfloat16((v2 - mu) * r * g[lane + 128] + be[lane + 128]);
  } else {                          // weight pack
    int idx = (bid - 2048) * 256 + threadIdx.x;
    if (idx < 147456) {                       // Wt1[n][k] = ipw[k][n]
      int n = idx / 192, k = idx - n * 192;
      Wt1[idx] = __float2bfloat16(ipw[(long)k * 768 + n]);
    } else if (idx < 147456 + 73728) {        // Wt2[j][d]
      int t = idx - 147456;
      int j = t / 384;
      float v = (j < 176) ? xpw[t] : 0.f;
      Wt2[t] = __float2bfloat16(v);
    } else if (idx < 147456 + 73728 + 73728) {// Wt3[n][k] = opw[k][n]
      int t = idx - 147456 - 73728;
      int n = t / 384, k = t - n * 384;
      Wt3[t] = __float2bfloat16(opw[(long)k * 192 + n]);
    }
  }
}

// direction map (involutions): pixel p <-> scan position l
__device__ __forceinline__ int inv_dir(int k, int p) {
  int pt = ((p & 63) << 6) | (p >> 6);
  if (k == 0) return p;
  if (k == 1) return pt;
  if (k == 2) return 4095 - p;
  return 4095 - pt;
}
__device__ __forceinline__ int dir_pix(int k, int l) { return inv_dir(k, l); }

// ---------------- bf16 MFMA GEMM: 64xTN tile, BK=64, XOR-swizzled LDS ----------------
template <int EPI, int TN>
__global__ __launch_bounds__(256) void k_gemm_mfma(const __hip_bfloat16* __restrict__ A,
                                                   const __hip_bfloat16* __restrict__ Bt,
                                                   const float* __restrict__ Res,
                                                   float* __restrict__ Co,
                                                   __hip_bfloat16* __restrict__ CoB,
                                                   __hip_bfloat16* __restrict__ Co2B,
                                                   float* __restrict__ dtsS,
                                                   float* __restrict__ BCs,
                                                   int M, int N, int Kk) {
  constexpr int NI = TN / 32;
  __shared__ __align__(16) short As[64 * 64];
  __shared__ __align__(16) short Bs[TN * 64];
  int tid = threadIdx.x;
  int wave = tid >> 6, lane = tid & 63;
  int mlane = lane & 15, quad = lane >> 4;
  int row0 = blockIdx.y * 64, col0 = blockIdx.x * TN;
  int wr = wave & 1, wc = wave >> 1;
  floatx4 acc[2][NI];
  #pragma unroll
  for (int mi = 0; mi < 2; mi++)
    #pragma unroll
    for (int ni = 0; ni < NI; ni++) acc[mi][ni] = (floatx4){0.f, 0.f, 0.f, 0.f};

  for (int k0 = 0; k0 < Kk; k0 += 64) {
    #pragma unroll
    for (int c = tid; c < 512; c += 256) {
      int r = c >> 3, j = c & 7;
      *(float4*)&As[r * 64 + ((j ^ (r & 7)) << 3)] =
          *(const float4*)&A[(long)(row0 + r) * Kk + k0 + j * 8];
    }
    #pragma unroll
    for (int c = tid; c < TN * 8; c += 256) {
      int r = c >> 3, j = c & 7;
      *(float4*)&Bs[r * 64 + ((j ^ (r & 7)) << 3)] =
          *(const float4*)&Bt[(long)(col0 + r) * Kk + k0 + j * 8];
    }
    __syncthreads();
    short8 af[2][2], bf[NI][2];
    #pragma unroll
    for (int mi = 0; mi < 2; mi++) {
      int r = wr * 32 + mi * 16 + mlane;
      #pragma unroll
      for (int kk = 0; kk < 2; kk++) {
        int jx = (kk * 4 + quad) ^ (r & 7);
        af[mi][kk] = *(const short8*)&As[r * 64 + jx * 8];
      }
    }
    #pragma unroll
    for (int ni = 0; ni < NI; ni++) {
      int rn = wc * (TN / 2) + ni * 16 + mlane;
      #pragma unroll
      for (int kk = 0; kk < 2; kk++) {
        int jx = (kk * 4 + quad) ^ (rn & 7);
        bf[ni][kk] = *(const short8*)&Bs[rn * 64 + jx * 8];
      }
    }
    #pragma unroll
    for (int kk = 0; kk < 2; kk++)
      #pragma unroll
      for (int mi = 0; mi < 2; mi++)
        #pragma unroll
        for (int ni = 0; ni < NI; ni++)
          acc[mi][ni] = __builtin_amdgcn_mfma_f32_16x16x32_bf16(af[mi][kk], bf[ni][kk],
                                                                acc[mi][ni], 0, 0, 0);
    __syncthreads();
  }
  // C/D layout: col=lane&15, row=quad*4+reg  [m89-verified]
  #pragma unroll
  for (int mi = 0; mi < 2; mi++) {
    #pragma unroll
    for (int ni = 0; ni < NI; ni++) {
      int cc = col0 + wc * (TN / 2) + ni * 16 + mlane;
      #pragma unroll
      for (int i = 0; i < 4; i++) {
        int rr = row0 + wr * 32 + mi * 16 + quad * 4 + i;
        float v = acc[mi][ni][i];
        if (EPI == 1) {
          Co[(long)rr * N + cc] = v + Res[(long)rr * N + cc];
        } else if (EPI == 2) {
          if (cc < 384) CoB[(long)rr * 384 + cc] = __float2bfloat16(v);
          else          Co2B[(long)rr * 384 + (cc - 384)] = __float2bfloat16(v);
        } else {  // EPI == 3: pixel-order split; B at 0..15, C at 16..31 of BCs row
          if (cc < 176) {
            int k4 = (cc >= 132) ? 3 : (cc >= 88) ? 2 : (cc >= 44) ? 1 : 0;
            int c = cc - k4 * 44;
            int b = rr >> 12, p = rr & 4095;
            long lbase = ((long)((b << 2) + k4) << 12) + p;   // pixel order
            if (c < 12) dtsS[lbase * 12 + c] = v;
            else        BCs[lbase * 32 + (c - 12)] = v;
          }
        }
      }
    }
  }
}

// ---------------- depthwise 3x3 conv + bias + SiLU; 2x4 pixels/block; bf16 in/out ----------------
__global__ __launch_bounds__(384) void k_conv(const __hip_bfloat16* __restrict__ xbufB,
                                              const float* __restrict__ cw,
                                              const float* __restrict__ cb,
                                              __hip_bfloat16* __restrict__ xcb) {
  int blk = blockIdx.x;            // 1024: b(2) x hgroup(32) x wgroup(16)
  int wg = blk & 15, hg = (blk >> 4) & 31, b = blk >> 9;
  int h0 = hg * 2, w0 = wg * 4;
  int d = threadIdx.x;
  float wt[9];
  const float* wp = cw + d * 9;
  #pragma unroll
  for (int i = 0; i < 9; i++) wt[i] = wp[i];
  float bias = cb[d];
  float v[4][6];
  #pragma unroll
  for (int r = 0; r < 4; r++) {
    int hh = h0 + r - 1;
    bool rok = (hh >= 0) && (hh < 64);
    #pragma unroll
    for (int c = 0; c < 6; c++) {
      int ww = w0 + c - 1;
      bool ok = rok && (ww >= 0) && (ww < 64);
      v[r][c] = ok ? __bfloat162float(xbufB[((long)(b << 12) + (hh << 6) + ww) * 384 + d]) : 0.f;
    }
  }
  #pragma unroll
  for (int i = 0; i < 2; i++) {
    #pragma unroll
    for (int j = 0; j < 4; j++) {
      float acc = bias;
      #pragma unroll
      for (int r = 0; r < 3; r++)
        #pragma unroll
        for (int c = 0; c < 3; c++)
          acc += v[i + r][j + c] * wt[r * 3 + c];
      float sg = 1.f / (1.f + __expf(-acc));
      xcb[((long)(b << 12) + ((h0 + i) << 6) + (w0 + j)) * 384 + d] = __float2bfloat16(acc * sg);
    }
  }
}

// ---------------- dt precompute: delta = softplus(dts @ dt_w^T + dt_b) -> fp16 plane ----------------
__global__ __launch_bounds__(384) void k_dt(const float* __restrict__ dtsS,
                                            const float* __restrict__ dt_w,
                                            const float* __restrict__ dt_b,
                                            __half* __restrict__ dpre) {
  int bid = blockIdx.x;
  int chunk = bid & 127, bk = bid >> 7;
  int k = bk & 3;
  int d = threadIdx.x;
  float w[12];
  const float* dwp = dt_w + ((long)(k * 384) + d) * 12;
  #pragma unroll
  for (int r = 0; r < 12; r++) w[r] = dwp[r];
  float db = dt_b[k * 384 + d];
  long base = ((long)bk << 12) + chunk * 32;
  #pragma unroll 4
  for (int t = 0; t < 32; t++) {
    const float4* dq = (const float4*)(dtsS + (base + t) * 12);
    float4 q0 = dq[0], q1 = dq[1], q2 = dq[2];
    float x = db + q0.x * w[0] + q0.y * w[1] + q0.z * w[2] + q0.w * w[3]
                 + q1.x * w[4] + q1.y * w[5] + q1.z * w[6] + q1.w * w[7]
                 + q2.x * w[8] + q2.y * w[9] + q2.z * w[10] + q2.w * w[11];
    float e = __expf(x);
    float delta = (x > 15.f) ? x : __logf(1.f + e);
    dpre[(base + t) * 384 + d] = __float2half(delta);
  }
}

// powers: pws[n] = r^(n+1), log-depth pairing
__device__ __forceinline__ void pow16(float r, float* pws) {
  pws[0] = r;
  #pragma unroll
  for (int n = 1; n < 16; n++) {
    int m = n + 1, c = (m + 1) / 2, f = m - c;
    pws[n] = pws[c - 1] * pws[f - 1];
  }
}

// ---------------- scan pass 0: 128 segments x 32 steps; E[16](fp16) + scalar cumDelta ----------------
__global__ __launch_bounds__(384) void k_scan0(
    const __half* __restrict__ dpre, const float* __restrict__ BCs,
    const __hip_bfloat16* __restrict__ xcb,
    const float* __restrict__ A_logs,
    __half* __restrict__ EbH, float* __restrict__ Dend) {
  int bid = blockIdx.x;
  int s = bid & 127, bk = bid >> 7;
  int k = bk & 3, b = bk >> 2;
  int d = threadIdx.x;
  const float* al = A_logs + ((long)(k * 384) + d) * 16;
  bool pw = true;
  float av[16];
  #pragma unroll
  for (int n = 0; n < 16; n++) {
    float a = __expf(al[n]);
    av[n] = -a;
    pw = pw && (fabsf(a - (float)(n + 1)) < 1e-3f);
  }
  float h[16];
  #pragma unroll
  for (int n = 0; n < 16; n++) h[n] = 0.f;
  float cum = 0.f;
  long bpk = (long)bk << 12;
  long bpix = (long)(b << 12);

  if (pw) {
    #pragma unroll 4
    for (int t = 0; t < 32; t++) {
      int p = dir_pix(k, s * 32 + t);
      float delta = __half2float(dpre[(bpk + p) * 384 + d]);
      float u = __bfloat162float(xcb[(bpix + p) * 384 + d]);
      cum += delta;
      float du = delta * u;
      float rr = __expf(-delta);
      float pws[16]; pow16(rr, pws);
      const float4* Bq = (const float4*)(BCs + (bpk + p) * 32);
      float4 b0 = Bq[0], b1 = Bq[1], b2 = Bq[2], b3 = Bq[3];
      float Bl[16] = {b0.x, b0.y, b0.z, b0.w, b1.x, b1.y, b1.z, b1.w,
                      b2.x, b2.y, b2.z, b2.w, b3.x, b3.y, b3.z, b3.w};
      #pragma unroll
      for (int n = 0; n < 16; n++) h[n] = pws[n] * h[n] + du * Bl[n];
    }
  } else {
    for (int t = 0; t < 32; t++) {
      int p = dir_pix(k, s * 32 + t);
      float delta = __half2float(dpre[(bpk + p) * 384 + d]);
      float u = __bfloat162float(xcb[(bpix + p) * 384 + d]);
      cum += delta;
      float du = delta * u;
      const float4* Bq = (const float4*)(BCs + (bpk + p) * 32);
      float4 b0 = Bq[0], b1 = Bq[1], b2 = Bq[2], b3 = Bq[3];
      float Bl[16] = {b0.x, b0.y, b0.z, b0.w, b1.x, b1.y, b1.z, b1.w,
                      b2.x, b2.y, b2.z, b2.w, b3.x, b3.y, b3.z, b3.w};
      #pragma unroll
      for (int n = 0; n < 16; n++) {
        float dA = __expf(delta * av[n]);
        h[n] = dA * h[n] + du * Bl[n];
      }
    }
  }
  long g = (long)bk * 128 + s;
  __half2* Ep = (__half2*)(EbH + g * 6144 + (long)d * 16);
  #pragma unroll
  for (int n = 0; n < 8; n++) {
    __half2 hv;
    hv.x = __float2half(h[2 * n]);
    hv.y = __float2half(h[2 * n + 1]);
    Ep[n] = hv;
  }
  Dend[g * 384 + d] = cum;
}

// ---------------- combine: Kogge-Stone over 128 segments; fp16 I/O, fp32 internal ----------------
__global__ __launch_bounds__(128) void k_combine(__half* __restrict__ EbH,
                                                 const float* __restrict__ Dend,
                                                 const float* __restrict__ A_logs) {
  int bid = blockIdx.x;            // bk*384 + d, 3072 blocks
  int bk = bid / 384;
  int d = bid - bk * 384;
  int k = bk & 3;
  int s = threadIdx.x;             // segment 0..127
  const float* al = A_logs + ((long)(k * 384) + d) * 16;
  bool pw = true;
  float av[16];
  #pragma unroll
  for (int n = 0; n < 16; n++) {
    float a = __expf(al[n]);
    av[n] = -a;
    pw = pw && (fabsf(a - (float)(n + 1)) < 1e-3f);
  }

  long ebase = ((long)bk * 128 + s) * 6144 + (long)d * 16;
  float e[16];
  {
    const __half2* Ein = (const __half2*)(EbH + ebase);
    #pragma unroll
    for (int n = 0; n < 8; n++) {
      __half2 hv = Ein[n];
      e[2 * n]     = __half2float(hv.x);
      e[2 * n + 1] = __half2float(hv.y);
    }
  }
  float sig = Dend[((long)bk * 128 + s) * 384 + d];

  __shared__ float sE[128][17];    // [s][0]=sigma, [s][1..16]=e
  sE[s][0] = sig;
  #pragma unroll
  for (int n = 0; n < 16; n++) sE[s][1 + n] = e[n];
  __syncthreads();

  for (int o = 1; o < 128; o <<= 1) {
    float ps = 0.f, pe[16];
    bool act = (s >= o);
    if (act) {
      ps = sE[s - o][0];
      #pragma unroll
      for (int n = 0; n < 16; n++) pe[n] = sE[s - o][1 + n];
    }
    __syncthreads();
    if (act) {
      if (pw) {
        float rc = __expf(-sig);
        float pwr[16]; pow16(rc, pwr);      // pwr[n] = exp(av[n]*sig), av[n]=-(n+1)
        #pragma unroll
        for (int n = 0; n < 16; n++) e[n] += pwr[n] * pe[n];
      } else {
        #pragma unroll
        for (int n = 0; n < 16; n++) e[n] += __expf(av[n] * sig) * pe[n];
      }
      sig += ps;
      sE[s][0] = sig;
      #pragma unroll
      for (int n = 0; n < 16; n++) sE[s][1 + n] = e[n];
    }
    __syncthreads();
  }

  float ho[16];
  if (s == 0) {
    #pragma unroll
    for (int n = 0; n < 16; n++) ho[n] = 0.f;
  } else {
    #pragma unroll
    for (int n = 0; n < 16; n++) ho[n] = sE[s - 1][1 + n];
  }
  __half2* Eo = (__half2*)(EbH + ebase);
  #pragma unroll
  for (int n = 0; n < 8; n++) {
    __half2 hv;
    hv.x = __float2half(ho[2 * n]);
    hv.y = __float2half(ho[2 * n + 1]);
    Eo[n] = hv;
  }
}

// ---------------- scan pass 1: full recurrence from h_in (fp16 in EbH) ----------------
// ATOMIC=0: store y bf16 into per-direction plane ybufB. ATOMIC=1: fp32 atomicAdd ysum.
template <int ATOMIC>
__global__ __launch_bounds__(384) void k_scan1(
    const __half* __restrict__ dpre, const float* __restrict__ BCs,
    const __hip_bfloat16* __restrict__ xcb,
    const float* __restrict__ A_logs, const __half* __restrict__ EbH,
    __hip_bfloat16* __restrict__ ybufB, float* __restrict__ ysum) {
  int bid = blockIdx.x;
  int s = bid & 127, bk = bid >> 7;
  int k = bk & 3, b = bk >> 2;
  int d = threadIdx.x;
  const float* al = A_logs + ((long)(k * 384) + d) * 16;
  bool pw = true;
  float av[16];
  #pragma unroll
  for (int n = 0; n < 16; n++) {
    float a = __expf(al[n]);
    av[n] = -a;
    pw = pw && (fabsf(a - (float)(n + 1)) < 1e-3f);
  }
  float h[16];
  {
    const __half2* hp = (const __half2*)(EbH + ((long)bk * 128 + s) * 6144 + (long)d * 16);
    #pragma unroll
    for (int n = 0; n < 8; n++) {
      __half2 hv = hp[n];
      h[2 * n]     = __half2float(hv.x);
      h[2 * n + 1] = __half2float(hv.y);
    }
  }
  long bpk = (long)bk << 12;
  long bpix = (long)(b << 12);

  if (pw) {
    #pragma unroll 4
    for (int t = 0; t < 32; t++) {
      int p = dir_pix(k, s * 32 + t);
      float delta = __half2float(dpre[(bpk + p) * 384 + d]);
      float u = __bfloat162float(xcb[(bpix + p) * 384 + d]);
      float du = delta * u;
      float rr = __expf(-delta);
      float pws[16]; pow16(rr, pws);
      const float4* Bq = (const float4*)(BCs + (bpk + p) * 32);
      float4 b0 = Bq[0], b1 = Bq[1], b2 = Bq[2], b3 = Bq[3];
      float Bl[16] = {b0.x, b0.y, b0.z, b0.w, b1.x, b1.y, b1.z, b1.w,
                      b2.x, b2.y, b2.z, b2.w, b3.x, b3.y, b3.z, b3.w};
      const float4* Cq = Bq + 4;
      float4 c0 = Cq[0], c1 = Cq[1], c2 = Cq[2], c3 = Cq[3];
      float Cl[16] = {c0.x, c0.y, c0.z, c0.w, c1.x, c1.y, c1.z, c1.w,
                      c2.x, c2.y, c2.z, c2.w, c3.x, c3.y, c3.z, c3.w};
      float y = 0.f;
      #pragma unroll
      for (int n = 0; n < 16; n++) { h[n] = pws[n] * h[n] + du * Bl[n]; y += h[n] * Cl[n]; }
      if (ATOMIC) atomicAdd(&ysum[(bpix + p) * 384 + d], y);
      else        ybufB[(bpk + p) * 384 + d] = __float2bfloat16(y);
    }
  } else {
    for (int t = 0; t < 32; t++) {
      int p = dir_pix(k, s * 32 + t);
      float delta = __half2float(dpre[(bpk + p) * 384 + d]);
      float u = __bfloat162float(xcb[(bpix + p) * 384 + d]);
      float du = delta * u;
      const float4* Bq = (const float4*)(BCs + (bpk + p) * 32);
      float4 b0 = Bq[0], b1 = Bq[1], b2 = Bq[2], b3 = Bq[3];
      float Bl[16] = {b0.x, b0.y, b0.z, b0.w, b1.x, b1.y, b1.z, b1.w,
                      b2.x, b2.y, b2.z, b2.w, b3.x, b3.y, b3.z, b3.w};
      const float4* Cq = Bq + 4;
      float4 c0 = Cq[0], c1 = Cq[1], c2 = Cq[2], c3 = Cq[3];
      float Cl[16] = {c0.x, c0.y, c0.z, c0.w, c1.x, c1.y, c1.z, c1.w,
                      c2.x, c2.y, c2.z, c2.w, c3.x, c3.y, c3.z, c3.w};
      float y = 0.f;
      #pragma unroll
      for (int n = 0; n < 16; n++) {
        float dA = __expf(delta * av[n]);
        h[n] = dA * h[n] + du * Bl[n];
        y += h[n] * Cl[n];
      }
      if (ATOMIC) atomicAdd(&ysum[(bpix + p) * 384 + d], y);
      else        ybufB[(bpk + p) * 384 + d] = __float2bfloat16(y);
    }
  }
}

// ---------------- merge: y + D-skip(bf16 xcb) + out-LN + silu(z bf16) -> bf16 ----------------
template <int GATHER>
__global__ __launch_bounds__(384) void k_merge(const __hip_bfloat16* __restrict__ yinB,
                                               const float* __restrict__ yinF,
                                               const __hip_bfloat16* __restrict__ xcb,
                                               const __hip_bfloat16* __restrict__ zbufB,
                                               const float* __restrict__ Ds,
                                               const float* __restrict__ g,
                                               const float* __restrict__ be,
                                               __hip_bfloat16* __restrict__ yactb) {
  int row = blockIdx.x;
  int d = threadIdx.x;
  float v;
  if (GATHER) {
    int b = row >> 12, p = row & 4095;
    long base = ((long)(b << 2) << 12) + p;  // plane (b*4+k)*4096 + p
    v = __bfloat162float(yinB[base * 384 + d])
      + __bfloat162float(yinB[(base + 4096) * 384 + d])
      + __bfloat162float(yinB[(base + 8192) * 384 + d])
      + __bfloat162float(yinB[(base + 12288) * 384 + d]);
  } else {
    v = yinF[(long)row * 384 + d];
  }
  float sd = Ds[d] + Ds[384 + d] + Ds[768 + d] + Ds[1152 + d];
  v += __bfloat162float(xcb[(long)row * 384 + d]) * sd;
  float s1 = v, s2 = v * v;
  #pragma unroll
  for (int o = 32; o > 0; o >>= 1) { s1 += __shfl_xor(s1, o); s2 += __shfl_xor(s2, o); }
  __shared__ float r1[6], r2[6];
  int wv = threadIdx.x >> 6;
  if ((threadIdx.x & 63) == 0) { r1[wv] = s1; r2[wv] = s2; }
  __syncthreads();
  float S1 = 0.f, S2 = 0.f;
  #pragma unroll
  for (int i = 0; i < 6; i++) { S1 += r1[i]; S2 += r2[i]; }
  float mu = S1 * (1.f / 384.f);
  float var = S2 * (1.f / 384.f) - mu * mu;
  float rr = rsqrtf(var + 1e-5f);
  float yn = (v - mu) * rr * g[d] + be[d];
  float z = __bfloat162float(zbufB[(long)row * 384 + d]);
  float sg = z / (1.f + __expf(-z));
  yactb[(long)row * 384 + d] = __float2bfloat16(yn * sg);
}

extern "C" void kernel_launch(void* const* d_in, const int* in_sizes, int n_in,
                              void* d_out, int out_size, void* d_ws, size_t ws_size,
                              hipStream_t stream) {
  const float* input      = (const float*)d_in[0];
  const float* norm_g     = (const float*)d_in[1];
  const float* norm_b     = (const float*)d_in[2];
  const float* in_proj_w  = (const float*)d_in[3];
  const float* conv_w     = (const float*)d_in[4];
  const float* conv_b     = (const float*)d_in[5];
  const float* x_proj_w   = (const float*)d_in[6];
  const float* dt_w       = (const float*)d_in[7];
  const float* dt_b       = (const float*)d_in[8];
  const float* A_logs     = (const float*)d_in[9];
  const float* Ds         = (const float*)d_in[10];
  const float* out_norm_g = (const float*)d_in[11];
  const float* out_norm_b = (const float*)d_in[12];
  const float* out_proj_w = (const float*)d_in[13];
  float* out = (float*)d_out;

  // plane path total = 24,788,992 floats (~99 MB); atomic fallback = 21,643,264 (~87 MB)
  bool big = ws_size >= (size_t)24788992 * 4;

  float* ws = (float*)d_ws;
  long o = 0;
  __hip_bfloat16* xnb   = (__hip_bfloat16*)(ws + o); o += 786432;   // 8192x192 bf16
  __hip_bfloat16* xbufB = (__hip_bfloat16*)(ws + o); o += 1572864;  // 8192x384 bf16
  __hip_bfloat16* zbufB = (__hip_bfloat16*)(ws + o); o += 1572864;
  __hip_bfloat16* xcb   = (__hip_bfloat16*)(ws + o); o += 1572864;
  __hip_bfloat16* Wt1   = (__hip_bfloat16*)(ws + o); o += 73728;    // 768x192 bf16
  __hip_bfloat16* Wt2   = (__hip_bfloat16*)(ws + o); o += 36864;
  __hip_bfloat16* Wt3   = (__hip_bfloat16*)(ws + o); o += 36864;
  float* dtsS           = ws + o;                    o += 393216;   // (BK,p,12) pixel order
  float* BCs            = ws + o;                    o += 1048576;  // (BK,p,32): B|C interleaved
  __half* dpre          = (__half*)(ws + o);         o += 6291456;  // (BK,p,384) fp16 delta
  __half* EbH           = (__half*)(ws + o);         o += 3145728;  // (1024 segs, 6144) fp16
  float* Dend           = ws + o;                    o += 393216;   // (1024, 384) fp32
  __hip_bfloat16* ybufB = (__hip_bfloat16*)(ws + o);
  float* ysum           = ws + o;                    o += big ? 6291456 : 3145728;
  __hip_bfloat16* yactb = (__hip_bfloat16*)(ws + o); o += 1572864;

  k_lnpackw<<<dim3(3200), dim3(256), 0, stream>>>(input, norm_g, norm_b, xnb,
                                                  in_proj_w, x_proj_w, out_proj_w, Wt1, Wt2, Wt3);
  k_gemm_mfma<2, 128><<<dim3(6, 128), dim3(256), 0, stream>>>(xnb, Wt1, nullptr, nullptr, xbufB, zbufB,
                                                              nullptr, nullptr, 8192, 768, 192);
  k_conv<<<dim3(1024), dim3(384), 0, stream>>>(xbufB, conv_w, conv_b, xcb);
  k_gemm_mfma<3, 64><<<dim3(3, 128), dim3(256), 0, stream>>>(xcb, Wt2, nullptr, nullptr, nullptr, nullptr,
                                                             dtsS, BCs, 8192, 192, 384);
  k_dt<<<dim3(1024), dim3(384), 0, stream>>>(dtsS, dt_w, dt_b, dpre);
  k_scan0<<<dim3(1024), dim3(384), 0, stream>>>(dpre, BCs, xcb, A_logs, EbH, Dend);
  k_combine<<<dim3(3072), dim3(128), 0, stream>>>(EbH, Dend, A_logs);
  if (big) {
    k_scan1<0><<<dim3(1024), dim3(384), 0, stream>>>(dpre, BCs, xcb, A_logs, EbH, ybufB, nullptr);
    k_merge<1><<<dim3(8192), dim3(384), 0, stream>>>(ybufB, nullptr, xcb, zbufB, Ds,
                                                     out_norm_g, out_norm_b, yactb);
  } else {
    hipMemsetAsync(ysum, 0, (size_t)3145728 * 4, stream);
    k_scan1<1><<<dim3(1024), dim3(384), 0, stream>>>(dpre, BCs, xcb, A_logs, EbH, nullptr, ysum);
    k_merge<0><<<dim3(8192), dim3(384), 0, stream>>>(nullptr, ysum, xcb, zbufB, Ds,
                                                     out_norm_g, out_norm_b, yactb);
  }
  k_gemm_mfma<1, 64><<<dim3(3, 128), dim3(256), 0, stream>>>(yactb, Wt3, input, out, nullptr, nullptr,
                                                             nullptr, nullptr, 8192, 192, 384);
}